// Round 8
// baseline (397.422 us; speedup 1.0000x reference)
//
#include <hip/hip_runtime.h>
#include <hip/hip_bf16.h>

typedef unsigned short u16;
typedef unsigned int   u32;
typedef __bf16 bf16x8 __attribute__((ext_vector_type(8)));
typedef float  f32x4  __attribute__((ext_vector_type(4)));

#define NB 4
#define T_ 2048
#define D_ 1024
#define H_ 16
#define DH 64
#define M_ (NB * T_)   // 8192 rows
#define PSTR 72        // padded LDS row stride (elements) for 64-wide tiles

__device__ __forceinline__ float bf2f(u16 u) {
    union { u32 i; float f; } v; v.i = ((u32)u) << 16; return v.f;
}
// manual RTNE round (compiler folds to ~3-4 VALU ops via v_add3)
__device__ __forceinline__ u16 f2bf(float f) {
    union { float fl; u32 i; } v; v.fl = f;
    u32 r = v.i + 0x7fff + ((v.i >> 16) & 1);
    return (u16)(r >> 16);
}

// async global->LDS, 16B per lane; lds base must be wave-uniform
__device__ __forceinline__ void gl_lds16(const u16* g, u16* l) {
    __builtin_amdgcn_global_load_lds((const __attribute__((address_space(1))) void*)g,
                                     (__attribute__((address_space(3))) void*)l,
                                     16, 0, 0);
}

// ---------------------------------------------------------- dtype detector
__device__ __forceinline__ int detect_f32(const u16* p) {
    int weird = 0;
    const int lane = threadIdx.x & 63;
    #pragma unroll
    for (int i = 0; i < 4; ++i) {
        const u16 u = p[lane * 4 + i];
        const int e = (u >> 7) & 0xFF;
        weird += (e == 0xFF || (e >= 0x01 && e <= 0x3F) || (e >= 0xC0 && e <= 0xFE));
    }
    #pragma unroll
    for (int off = 32; off; off >>= 1) weird += __shfl_xor(weird, off);
    return weird >= 16;
}

// int32/int64-tolerant sequence-length read
__device__ __forceinline__ int read_len(const void* raw, int b) {
    const int* a32 = (const int*)raw;
    bool ok32 = true;
    #pragma unroll
    for (int i = 0; i < NB; ++i) {
        const int v = a32[i];
        if (v < 1 || v > T_) ok32 = false;
    }
    int v = ok32 ? a32[b] : (int)((const long long*)raw)[b];
    return min(max(v, 1), T_);
}

// ---------------------------------------------------------------- fused prep
// blocks [0, 8192)            : LayerNorm rows
// blocks [8192, 8192+1024)    : weight transpose tiles (4 weights x 256 tiles)
// blocks [9216, 9216+256)     : RoPE cos/sin table (+ work-queue counter reset)
__global__ __launch_bounds__(256) void prep_kernel(const void* __restrict__ xraw,
                                                   const void* __restrict__ graw,
                                                   const void* __restrict__ braw,
                                                   u16* __restrict__ h,
                                                   const void* __restrict__ W0,
                                                   const void* __restrict__ W1,
                                                   const void* __restrict__ W2,
                                                   const void* __restrict__ W3,
                                                   u16* __restrict__ Wt0,
                                                   u16* __restrict__ Wt1,
                                                   u16* __restrict__ Wt2,
                                                   u16* __restrict__ Wt3,
                                                   float2* __restrict__ tab,
                                                   u32* __restrict__ ctr) {
    __shared__ __align__(16) u16 sh[64 * PSTR];
    const int bid = blockIdx.x;
    const int tid = threadIdx.x;

    if (bid < M_) {
        // ---- LayerNorm ----
        const int row = bid;
        const int isf = detect_f32((const u16*)xraw);
        float* red = (float*)sh;

        float xv[4];
        if (isf) {
            const float* xr = (const float*)xraw + (size_t)row * D_;
            *(float4*)xv = *(const float4*)&xr[tid * 4];
        } else {
            const u16* xr = (const u16*)xraw + (size_t)row * D_;
            u16 loc[4] __attribute__((aligned(8)));
            *(uint2*)loc = *(const uint2*)&xr[tid * 4];
            #pragma unroll
            for (int i = 0; i < 4; ++i) xv[i] = bf2f(loc[i]);
        }

        float s = xv[0] + xv[1] + xv[2] + xv[3];
        float q = xv[0]*xv[0] + xv[1]*xv[1] + xv[2]*xv[2] + xv[3]*xv[3];
        #pragma unroll
        for (int off = 32; off; off >>= 1) {
            s += __shfl_xor(s, off);
            q += __shfl_xor(q, off);
        }
        const int wave = tid >> 6, lane = tid & 63;
        if (lane == 0) { red[wave] = s; red[4 + wave] = q; }
        __syncthreads();
        s = red[0] + red[1] + red[2] + red[3];
        q = red[4] + red[5] + red[6] + red[7];

        const float mean = s * (1.0f / D_);
        const float var  = q * (1.0f / D_) - mean * mean;
        const float rs   = rsqrtf(var + 1e-5f);

        u16 o[4] __attribute__((aligned(8)));
        #pragma unroll
        for (int i = 0; i < 4; ++i) {
            const int c = tid * 4 + i;
            const float gv = isf ? ((const float*)graw)[c] : bf2f(((const u16*)graw)[c]);
            const float bv = isf ? ((const float*)braw)[c] : bf2f(((const u16*)braw)[c]);
            o[i] = f2bf((xv[i] - mean) * rs * gv + bv);
        }
        *(uint2*)&h[(size_t)row * D_ + tid * 4] = *(uint2*)o;
    } else if (bid < M_ + 1024) {
        // ---- weight transpose+convert ----
        const int w = bid - M_;
        const int z = w >> 8;            // weight index 0..3
        const int t = w & 255;
        const void* Wraw = (z == 0) ? W0 : (z == 1) ? W1 : (z == 2) ? W2 : W3;
        u16* Wt          = (z == 0) ? Wt0 : (z == 1) ? Wt1 : (z == 2) ? Wt2 : Wt3;
        u16 (*tile)[PSTR] = (u16(*)[PSTR])sh;
        const int isf = detect_f32((const u16*)Wraw);
        const int n0 = (t & 15) * 64;
        const int k0 = (t >> 4) * 64;
        const int tr  = tid >> 2;          // 0..63
        const int tc  = (tid & 3) * 16;    // 0,16,32,48

        if (isf) {
            const float* W = (const float*)Wraw;
            #pragma unroll
            for (int i = 0; i < 16; ++i)
                tile[tc + i][tr] = f2bf(W[(size_t)(k0 + tr) * D_ + n0 + tc + i]);
        } else {
            const u16* W = (const u16*)Wraw;
            #pragma unroll
            for (int i = 0; i < 16; ++i)
                tile[tc + i][tr] = W[(size_t)(k0 + tr) * D_ + n0 + tc + i];
        }
        __syncthreads();
        *(uint4*)&Wt[(size_t)(n0 + tr) * D_ + k0 + tc]     = *(uint4*)&tile[tr][tc];
        *(uint4*)&Wt[(size_t)(n0 + tr) * D_ + k0 + tc + 8] = *(uint4*)&tile[tr][tc + 8];
    } else {
        // ---- RoPE table: tab[t*32+i] = {cos, sin}(t * 10000^(-i/32)) ----
        const int gid = (bid - (M_ + 1024)) * 256 + tid;  // 0..65535
        if (gid == 0 && ctr) ctr[0] = 0;                  // reset attn work queue
        const int t = gid >> 5, i = gid & 31;
        const float inv = exp2f(-(float)i * 0.41524101186092f);
        const float ang = (float)t * inv;
        float sv, cv;
        sincosf(ang, &sv, &cv);
        tab[gid] = make_float2(cv, sv);
    }
}

// single-weight transpose (fallback path)
__global__ __launch_bounds__(256) void wconv_kernel(const void* __restrict__ Wraw,
                                                    u16* __restrict__ Wt) {
    __shared__ u16 tile[64][PSTR];
    const int isf = detect_f32((const u16*)Wraw);
    const int n0 = blockIdx.x * 64;
    const int k0 = blockIdx.y * 64;
    const int tid = threadIdx.x;
    const int tr  = tid >> 2;
    const int tc  = (tid & 3) * 16;

    if (isf) {
        const float* W = (const float*)Wraw;
        #pragma unroll
        for (int i = 0; i < 16; ++i)
            tile[tc + i][tr] = f2bf(W[(size_t)(k0 + tr) * D_ + n0 + tc + i]);
    } else {
        const u16* W = (const u16*)Wraw;
        #pragma unroll
        for (int i = 0; i < 16; ++i)
            tile[tc + i][tr] = W[(size_t)(k0 + tr) * D_ + n0 + tc + i];
    }
    __syncthreads();
    *(uint4*)&Wt[(size_t)(n0 + tr) * D_ + k0 + tc]     = *(uint4*)&tile[tr][tc];
    *(uint4*)&Wt[(size_t)(n0 + tr) * D_ + k0 + tc + 8] = *(uint4*)&tile[tr][tc + 8];
}

// --------------------------------------------------- V transpose (per head)
// vtmp (M, D) row-major -> vt (N, H, DH, T)
__global__ __launch_bounds__(256) void vtrans_kernel(const u16* __restrict__ vtmp,
                                                     u16* __restrict__ vt) {
    __shared__ u16 tile[64][PSTR];
    const int bh = blockIdx.y;
    const int b  = bh >> 4;
    const int hh = bh & 15;
    const int t0 = blockIdx.x * 64;
    const int tid = threadIdx.x;
    const int tr  = tid >> 2;          // 0..63
    const int tc  = (tid & 3) * 16;

    #pragma unroll
    for (int i = 0; i < 16; ++i)   // tile[d][t]
        tile[tc + i][tr] = vtmp[(size_t)(b * T_ + t0 + tr) * D_ + hh * DH + tc + i];
    __syncthreads();
    u16* dst = vt + (size_t)bh * DH * T_ + (size_t)tr * T_ + t0;
    *(uint4*)&dst[tc]     = *(uint4*)&tile[tr][tc];
    *(uint4*)&dst[tc + 8] = *(uint4*)&tile[tr][tc + 8];
}

// ---------------------------------------------------------------- fused QKV GEMM (256x256)
// T3 minimum-2-phase: double-buffered LDS, stage NEXT K-tile first, then
// ds_read+MFMA of current, ONE barrier per K-step (its implicit vmcnt(0)
// drain lands the staged tile; loads overlap the whole compute phase).
// 512 threads = 8 waves (2M x 4N), per-wave output 128x64, BK=32.
// Grid 384 blocks (32 mtiles x 12 ntiles), all co-resident at 2 blocks/CU.
// Outputs ROW-MAJOR (M, D); Q,K: table RoPE.
__global__ __launch_bounds__(512) void qkv256_kernel(const u16* __restrict__ A,
                                                     const u16* __restrict__ Wt3,
                                                     const void* __restrict__ Braw,
                                                     const void* __restrict__ bqr,
                                                     const void* __restrict__ bkr,
                                                     const void* __restrict__ bvr,
                                                     u16* __restrict__ qo,
                                                     u16* __restrict__ ko,
                                                     u16* __restrict__ vo,
                                                     const float2* __restrict__ tab) {
    __shared__ __align__(16) u16 As[2][256 * 32];
    __shared__ __align__(16) u16 Bs[2][256 * 32];

    const int tid  = threadIdx.x;
    const int wave = tid >> 6;          // 0..7
    const int lane = tid & 63;
    const int quad = lane >> 4;
    const int lr   = lane & 15;
    const int wr   = wave >> 2;         // 0..1 (M)
    const int wc   = wave & 3;          // 0..3 (N)

    // chunked XCD swizzle: 384 = 8 * 48
    const int bid = blockIdx.x;
    const int wg  = (bid & 7) * 48 + (bid >> 3);
    const int ntile = (wg % 12) * 256;      // 0..2816 (never crosses seg bound)
    const int mtile = (wg / 12) * 256;
    const int seg   = ntile >> 10;          // 0=Q 1=K 2=V

    const int isf = detect_f32((const u16*)Braw);

    // staging: issue j in {0,1} covers rows j*128 + wave*16 + lane/4
    const int srow = wave * 16 + (lane >> 2);
    const int scol = (lane & 3) * 8;
    const u16* aP0 = A   + (size_t)(mtile + srow) * D_ + scol;
    const u16* aP1 = A   + (size_t)(mtile + 128 + srow) * D_ + scol;
    const u16* bP0 = Wt3 + (size_t)(ntile + srow) * D_ + scol;
    const u16* bP1 = Wt3 + (size_t)(ntile + 128 + srow) * D_ + scol;
    const int lo0 = (wave * 16) * 32;         // wave-uniform LDS offsets
    const int lo1 = (128 + wave * 16) * 32;

    f32x4 acc[8][4];
    #pragma unroll
    for (int m = 0; m < 8; ++m)
        #pragma unroll
        for (int n = 0; n < 4; ++n)
            acc[m][n] = (f32x4){0.f, 0.f, 0.f, 0.f};

    // prologue: stage K-tile 0 into buf 0
    gl_lds16(aP0, &As[0][lo0]);
    gl_lds16(aP1, &As[0][lo1]);
    gl_lds16(bP0, &Bs[0][lo0]);
    gl_lds16(bP1, &Bs[0][lo1]);
    __syncthreads();

    int cur = 0;
    for (int kk = 0; kk < D_ / 32; ++kk) {
        const int nxt = cur ^ 1;
        if (kk + 1 < D_ / 32) {
            const int k0 = (kk + 1) * 32;
            gl_lds16(aP0 + k0, &As[nxt][lo0]);
            gl_lds16(aP1 + k0, &As[nxt][lo1]);
            gl_lds16(bP0 + k0, &Bs[nxt][lo0]);
            gl_lds16(bP1 + k0, &Bs[nxt][lo1]);
        }

        bf16x8 af[8], bfr[4];
        #pragma unroll
        for (int m = 0; m < 8; ++m)
            af[m] = *(const bf16x8*)&As[cur][(wr * 128 + m * 16 + lr) * 32 + quad * 8];
        #pragma unroll
        for (int n = 0; n < 4; ++n)
            bfr[n] = *(const bf16x8*)&Bs[cur][(wc * 64 + n * 16 + lr) * 32 + quad * 8];

        __builtin_amdgcn_s_setprio(1);
        #pragma unroll
        for (int m = 0; m < 8; ++m)
            #pragma unroll
            for (int n = 0; n < 4; ++n)
                acc[m][n] = __builtin_amdgcn_mfma_f32_16x16x32_bf16(af[m], bfr[n], acc[m][n], 0, 0, 0);
        __builtin_amdgcn_s_setprio(0);

        __syncthreads();   // drains vmcnt(0) (staged tile ready) + read-before-overwrite
        cur = nxt;
    }

    const void* biasraw = (seg == 0) ? bqr : (seg == 1) ? bkr : bvr;
    u16* out            = (seg == 0) ? qo  : (seg == 1) ? ko  : vo;
    const int nloc = (ntile & 1023) + wc * 64;

    #pragma unroll
    for (int m = 0; m < 8; ++m) {
        #pragma unroll
        for (int n = 0; n < 4; ++n) {
            const int ncl = nloc + n * 16 + lr;       // 0..1023 within segment
            const float bv = isf ? ((const float*)biasraw)[ncl]
                                 : bf2f(((const u16*)biasraw)[ncl]);
            #pragma unroll
            for (int r = 0; r < 4; ++r) {
                const int mrow = mtile + wr * 128 + m * 16 + quad * 4 + r;
                float v = acc[m][n][r] + bv;
                if (seg < 2) {
                    const float other = __shfl_xor(v, 1);
                    const int d = ncl & (DH - 1);
                    const int t = mrow & (T_ - 1);
                    const float2 cs = tab[t * 32 + (d >> 1)];
                    v = (d & 1) ? (other * cs.y + v * cs.x) : (v * cs.x - other * cs.y);
                }
                out[(size_t)mrow * D_ + ncl] = f2bf(v);
            }
        }
    }
}

// ---------------------------------------------------------------- GEMM (128x128, dbuf 2-phase)
// Same T3 minimum-2-phase structure at 128² / BK=32 (LDS 32 KB, 5 blocks/CU).
// mode 0: row-major store; mode 1: V-transposed scatter; mode 2: RoPE scatter
__global__ __launch_bounds__(256) void gemm128_kernel(const u16* __restrict__ A,
                                                      const u16* __restrict__ Bt,
                                                      const void* __restrict__ Braw,
                                                      const void* __restrict__ biasraw,
                                                      void* __restrict__ out,
                                                      const int nx,
                                                      const int mode) {
    __shared__ __align__(16) u16 As[2][128 * 32];
    __shared__ __align__(16) u16 Bs[2][128 * 32];

    const int tid   = threadIdx.x;
    const int wave  = tid >> 6;
    const int lane  = tid & 63;
    const int quad  = lane >> 4;
    const int lr    = lane & 15;

    // chunked XCD swizzle (nwg = nx * 64, divisible by 8)
    const int bid = blockIdx.x;
    const int cpx = (nx * (M_ / 128)) >> 3;
    const int wg  = (bid & 7) * cpx + (bid >> 3);
    const int ntile = (wg % nx) * 128;
    const int mtile = (wg / nx) * 128;

    const int isf = detect_f32((const u16*)Braw);

    // staging: issue j in {0,1} covers rows j*64 + wave*16 + lane/4
    const int srow = wave * 16 + (lane >> 2);
    const int scol = (lane & 3) * 8;
    const u16* aP0 = A  + (size_t)(mtile + srow) * D_ + scol;
    const u16* aP1 = A  + (size_t)(mtile + 64 + srow) * D_ + scol;
    const u16* bP0 = Bt + (size_t)(ntile + srow) * D_ + scol;
    const u16* bP1 = Bt + (size_t)(ntile + 64 + srow) * D_ + scol;
    const int lo0 = (wave * 16) * 32;
    const int lo1 = (64 + wave * 16) * 32;

    const int mbase = (wave >> 1) * 64;
    const int nbase = (wave & 1) * 64;

    f32x4 acc[4][4];
    #pragma unroll
    for (int m = 0; m < 4; ++m)
        #pragma unroll
        for (int n = 0; n < 4; ++n)
            acc[m][n] = (f32x4){0.f, 0.f, 0.f, 0.f};

    // prologue
    gl_lds16(aP0, &As[0][lo0]);
    gl_lds16(aP1, &As[0][lo1]);
    gl_lds16(bP0, &Bs[0][lo0]);
    gl_lds16(bP1, &Bs[0][lo1]);
    __syncthreads();

    int cur = 0;
    for (int kk = 0; kk < D_ / 32; ++kk) {
        const int nxt = cur ^ 1;
        if (kk + 1 < D_ / 32) {
            const int k0 = (kk + 1) * 32;
            gl_lds16(aP0 + k0, &As[nxt][lo0]);
            gl_lds16(aP1 + k0, &As[nxt][lo1]);
            gl_lds16(bP0 + k0, &Bs[nxt][lo0]);
            gl_lds16(bP1 + k0, &Bs[nxt][lo1]);
        }

        bf16x8 af[4], bfr[4];
        #pragma unroll
        for (int m = 0; m < 4; ++m)
            af[m] = *(const bf16x8*)&As[cur][(mbase + m * 16 + lr) * 32 + quad * 8];
        #pragma unroll
        for (int n = 0; n < 4; ++n)
            bfr[n] = *(const bf16x8*)&Bs[cur][(nbase + n * 16 + lr) * 32 + quad * 8];

        __builtin_amdgcn_s_setprio(1);
        #pragma unroll
        for (int m = 0; m < 4; ++m)
            #pragma unroll
            for (int n = 0; n < 4; ++n)
                acc[m][n] = __builtin_amdgcn_mfma_f32_16x16x32_bf16(af[m], bfr[n], acc[m][n], 0, 0, 0);
        __builtin_amdgcn_s_setprio(0);

        __syncthreads();
        cur = nxt;
    }

    #pragma unroll
    for (int m = 0; m < 4; ++m) {
        #pragma unroll
        for (int n = 0; n < 4; ++n) {
            const int ncol = ntile + nbase + n * 16 + lr;
            const float bv = isf ? ((const float*)biasraw)[ncol]
                                 : bf2f(((const u16*)biasraw)[ncol]);
            #pragma unroll
            for (int r = 0; r < 4; ++r) {
                const int mrow = mtile + mbase + m * 16 + quad * 4 + r;
                float v = acc[m][n][r] + bv;
                if (mode == 2) {
                    const float other = __shfl_xor(v, 1);
                    const int d = ncol & (DH - 1);
                    const int t = mrow & (T_ - 1);
                    const int i = d >> 1;
                    const float inv = exp2f(-(float)i * 0.41524101186092f);
                    const float ang = (float)t * inv;
                    float sv, cv;
                    __sincosf(ang, &sv, &cv);
                    v = (d & 1) ? (other * sv + v * cv) : (v * cv - other * sv);
                }
                const int d  = ncol & (DH - 1);
                const int hh = ncol >> 6;
                const int t  = mrow & (T_ - 1);
                const int bb = mrow >> 11;
                if (mode == 0) {
                    if (isf) ((float*)out)[(size_t)mrow * D_ + ncol] = v;
                    else     ((u16*)out)[(size_t)mrow * D_ + ncol] = f2bf(v);
                } else if (mode == 1) {
                    ((u16*)out)[(((size_t)(bb * H_ + hh) * DH) + d) * T_ + t] = f2bf(v);
                } else {
                    ((u16*)out)[(((size_t)(bb * H_ + hh) * T_) + t) * DH + d] = f2bf(v);
                }
            }
        }
    }
}

// ---------------------------------------------------------------- GEMM (no-wt fallback)
__global__ __launch_bounds__(256) void gemm_kernel(const u16* __restrict__ A,
                                                   const void* __restrict__ Braw,
                                                   const void* __restrict__ biasraw,
                                                   void* __restrict__ out,
                                                   const int mode) {
    __shared__ __align__(16) u16 As[128 * 32];
    __shared__ __align__(16) u16 Bs[64 * 32];

    const int tid   = threadIdx.x;
    const int ntile = blockIdx.x * 64;
    const int mtile = blockIdx.y * 128;
    const int wave  = tid >> 6;
    const int lane  = tid & 63;
    const int quad  = lane >> 4;
    const int lr    = lane & 15;

    const int isf = detect_f32((const u16*)Braw);
    const float* Bf = (const float*)Braw;
    const u16*   Bu = (const u16*)Braw;

    f32x4 acc[2][4];
    #pragma unroll
    for (int s = 0; s < 2; ++s)
        #pragma unroll
        for (int n = 0; n < 4; ++n)
            acc[s][n] = (f32x4){0.f, 0.f, 0.f, 0.f};

    const int ar  = tid >> 1;
    const int akb = (tid & 1) * 16;
    const int bn  = tid & 63;
    const int bkb = (tid >> 6) * 8;
    const u16* Arow = A + (size_t)(mtile + ar) * D_ + akb;
    const size_t bcol0 = (size_t)bkb * D_ + ntile + bn;

    for (int k0 = 0; k0 < D_; k0 += 32) {
        *(uint4*)&As[ar * 32 + akb]     = *(const uint4*)(Arow + k0);
        *(uint4*)&As[ar * 32 + akb + 8] = *(const uint4*)(Arow + k0 + 8);
        {
            u16 tmp[8] __attribute__((aligned(16)));
            if (isf) {
                #pragma unroll
                for (int j = 0; j < 8; ++j) tmp[j] = f2bf(Bf[bcol0 + (size_t)(k0 + j) * D_]);
            } else {
                #pragma unroll
                for (int j = 0; j < 8; ++j) tmp[j] = Bu[bcol0 + (size_t)(k0 + j) * D_];
            }
            *(uint4*)&Bs[bn * 32 + bkb] = *(uint4*)tmp;
        }
        __syncthreads();

        const int mbase = wave * 32;
        bf16x8 af0 = *(const bf16x8*)&As[(mbase +      lr) * 32 + quad * 8];
        bf16x8 af1 = *(const bf16x8*)&As[(mbase + 16 + lr) * 32 + quad * 8];
        #pragma unroll
        for (int nt = 0; nt < 4; ++nt) {
            bf16x8 bf = *(const bf16x8*)&Bs[(nt * 16 + lr) * 32 + quad * 8];
            acc[0][nt] = __builtin_amdgcn_mfma_f32_16x16x32_bf16(af0, bf, acc[0][nt], 0, 0, 0);
            acc[1][nt] = __builtin_amdgcn_mfma_f32_16x16x32_bf16(af1, bf, acc[1][nt], 0, 0, 0);
        }
        __syncthreads();
    }

    #pragma unroll
    for (int s2 = 0; s2 < 2; ++s2) {
        #pragma unroll
        for (int nt = 0; nt < 4; ++nt) {
            const int ncol = ntile + nt * 16 + lr;
            const float bv = isf ? ((const float*)biasraw)[ncol]
                                 : bf2f(((const u16*)biasraw)[ncol]);
            #pragma unroll
            for (int r = 0; r < 4; ++r) {
                const int mrow = mtile + wave * 32 + s2 * 16 + quad * 4 + r;
                float v = acc[s2][nt][r] + bv;
                if (mode == 2) {
                    const float other = __shfl_xor(v, 1);
                    const int d = ncol & (DH - 1);
                    const int t = mrow & (T_ - 1);
                    const int i = d >> 1;
                    const float inv = exp2f(-(float)i * 0.41524101186092f);
                    const float ang = (float)t * inv;
                    const float cv = cosf(ang), sv = sinf(ang);
                    v = (d & 1) ? (other * sv + v * cv) : (v * cv - other * sv);
                }
                const int d  = ncol & (DH - 1);
                const int hh = ncol >> 6;
                const int t  = mrow & (T_ - 1);
                const int bb = mrow >> 11;
                if (mode == 0) {
                    if (isf) ((float*)out)[(size_t)mrow * D_ + ncol] = v;
                    else     ((u16*)out)[(size_t)mrow * D_ + ncol] = f2bf(v);
                } else if (mode == 1) {
                    ((u16*)out)[(((size_t)(bb * H_ + hh) * DH) + d) * T_ + t] = f2bf(v);
                } else {
                    ((u16*)out)[(((size_t)(bb * H_ + hh) * T_) + t) * DH + d] = f2bf(v);
                }
            }
        }
    }
}

// ---------------------------------------------------------------- attention
// Persistent-block work-queue flash attention, FIXED-MAX softmax:
//   p = exp2(C2 * rcp(z+1)), z = exp2(s*C1)   -- raw v_exp/v_rcp only
// Work items = 2048 (bh, q-tile) units ordered q-tile DESCENDING (LPT).
// ctr != nullptr: 1024 persistent blocks pull items via device atomicAdd
// (counter zeroed by prep each replay). ctr == nullptr: item = blockIdx.x.
// Inner loop: reg prefetch, 2 barriers/tile, no-barrier wave-private
// softmax->PV, setprio around MFMA.
// rowmajor=1: Q/K are (M, D); rowmajor=0: (N,H,T,DH).
__global__ __launch_bounds__(256) void attn_kernel(const u16* __restrict__ Q,
                                                   const u16* __restrict__ K,
                                                   const u16* __restrict__ Vt,
                                                   const void* __restrict__ lensraw,
                                                   u16* __restrict__ ctx,
                                                   u32* __restrict__ ctr,
                                                   const int rowmajor) {
    __shared__ __align__(16) u16 Ps[64 * PSTR];    // Q staging, then P tile
    __shared__ __align__(16) u16 Ks[64 * PSTR];
    __shared__ __align__(16) u16 Vts[64 * PSTR];   // [dim][key]
    __shared__ int item_s;

    const int tid  = threadIdx.x;
    const int wave = tid >> 6;
    const int lane = tid & 63;
    const int quad = lane >> 4;
    const int lr   = lane & 15;
    const int srow = tid >> 2;          // wave w covers rows 16w..16w+15
    const int scb  = (tid & 3) * 16;
    const int prow = wave * 16 + quad * 4;

    const float C1 = 1.44269504f / 120.0f;   // log2e / 120
    const float C2 = -60.0f * 1.44269504f;   // -60 * log2e

    for (int iter = 0; ; ++iter) {
        if (tid == 0)
            item_s = ctr ? (int)atomicAdd(ctr, 1u)
                         : (iter == 0 ? (int)blockIdx.x : NB * H_ * 32);
        __syncthreads();   // broadcast; also guards LDS reuse across items
        const int item = item_s;
        if (item >= NB * H_ * 32) break;

        // LPT mapping: longest q-tiles first
        const int qt = 31 - (item >> 6);   // 31..0
        const int bh = item & 63;
        const int qs = qt * 64;
        const int b  = bh >> 4;
        const int hh = bh & 15;
        const int len = read_len(lensraw, b);

        const size_t qkstride = rowmajor ? (size_t)D_ : (size_t)DH;
        const size_t qkoff    = rowmajor ? ((size_t)b * T_ * D_ + hh * DH)
                                         : ((size_t)bh * T_ * DH);
        const u16* Qp = Q + qkoff;
        const u16* Kp = K + qkoff;
        const u16* Vb = Vt + (size_t)bh * DH * T_;

        // Q staging (wave-private rows; no barrier needed) + K/V tile 0
        *(uint4*)&Ps[srow * PSTR + scb]     = *(const uint4*)&Qp[(size_t)(qs + srow) * qkstride + scb];
        *(uint4*)&Ps[srow * PSTR + scb + 8] = *(const uint4*)&Qp[(size_t)(qs + srow) * qkstride + scb + 8];
        const bf16x8 qa0 = *(const bf16x8*)&Ps[(wave * 16 + lr) * PSTR + quad * 8];
        const bf16x8 qa1 = *(const bf16x8*)&Ps[(wave * 16 + lr) * PSTR + 32 + quad * 8];
        {
            uint4 k0 = *(const uint4*)&Kp[(size_t)srow * qkstride + scb];
            uint4 k1 = *(const uint4*)&Kp[(size_t)srow * qkstride + scb + 8];
            uint4 v0 = *(const uint4*)&Vb[(size_t)srow * T_ + scb];
            uint4 v1 = *(const uint4*)&Vb[(size_t)srow * T_ + scb + 8];
            *(uint4*)&Ks[srow * PSTR + scb]      = k0;
            *(uint4*)&Ks[srow * PSTR + scb + 8]  = k1;
            *(uint4*)&Vts[srow * PSTR + scb]     = v0;
            *(uint4*)&Vts[srow * PSTR + scb + 8] = v1;
        }
        __syncthreads();

        f32x4 acc[4];
        float l_loc[4] = {0.f, 0.f, 0.f, 0.f};
        #pragma unroll
        for (int nt = 0; nt < 4; ++nt) acc[nt] = (f32x4){0.f, 0.f, 0.f, 0.f};

        const int ktn = min(qs + 63, len - 1) / 64 + 1;

        uint4 kr0, kr1, vr0, vr1;
        for (int kt = 0; kt < ktn; ++kt) {
            const int ks = kt * 64;
            const bool havenext = (kt + 1 < ktn);   // block-uniform

            if (havenext) {
                const int ns = ks + 64;
                kr0 = *(const uint4*)&Kp[(size_t)(ns + srow) * qkstride + scb];
                kr1 = *(const uint4*)&Kp[(size_t)(ns + srow) * qkstride + scb + 8];
                vr0 = *(const uint4*)&Vb[(size_t)srow * T_ + ns + scb];
                vr1 = *(const uint4*)&Vb[(size_t)srow * T_ + ns + scb + 8];
            }

            // QK^T
            f32x4 s[4];
            #pragma unroll
            for (int nt = 0; nt < 4; ++nt) s[nt] = (f32x4){0.f, 0.f, 0.f, 0.f};
            __builtin_amdgcn_s_setprio(1);
            #pragma unroll
            for (int nt = 0; nt < 4; ++nt) {
                bf16x8 kb0 = *(const bf16x8*)&Ks[(nt * 16 + lr) * PSTR + quad * 8];
                bf16x8 kb1 = *(const bf16x8*)&Ks[(nt * 16 + lr) * PSTR + 32 + quad * 8];
                s[nt] = __builtin_amdgcn_mfma_f32_16x16x32_bf16(qa0, kb0, s[nt], 0, 0, 0);
                s[nt] = __builtin_amdgcn_mfma_f32_16x16x32_bf16(qa1, kb1, s[nt], 0, 0, 0);
            }
            __builtin_amdgcn_s_setprio(0);

            // fixed-max softmax; masking only on diagonal / len-boundary tiles
            const bool need_mask = (ks == qs) || (ks + 63 >= len);
            if (!need_mask) {
                #pragma unroll
                for (int r = 0; r < 4; ++r) {
                    #pragma unroll
                    for (int nt = 0; nt < 4; ++nt) {
                        const float z = __builtin_amdgcn_exp2f(s[nt][r] * C1);
                        const float p = __builtin_amdgcn_exp2f(C2 * __builtin_amdgcn_rcpf(z + 1.0f));
                        l_loc[r] += p;
                        Ps[(prow + r) * PSTR + nt * 16 + lr] = f2bf(p);
                    }
                }
            } else {
                #pragma unroll
                for (int r = 0; r < 4; ++r) {
                    const int trow = qs + prow + r;
                    #pragma unroll
                    for (int nt = 0; nt < 4; ++nt) {
                        const float z = __builtin_amdgcn_exp2f(s[nt][r] * C1);
                        float p = __builtin_amdgcn_exp2f(C2 * __builtin_amdgcn_rcpf(z + 1.0f));
                        const int col = ks + nt * 16 + lr;
                        p = (col > trow || col >= len) ? 0.f : p;
                        l_loc[r] += p;
                        Ps[(prow + r) * PSTR + nt * 16 + lr] = f2bf(p);
                    }
                }
            }
            // no barrier: Ps rows are wave-private

            // PV
            bf16x8 pa0 = *(const bf16x8*)&Ps[(wave * 16 + lr) * PSTR + quad * 8];
            bf16x8 pa1 = *(const bf16x8*)&Ps[(wave * 16 + lr) * PSTR + 32 + quad * 8];
            __builtin_amdgcn_s_setprio(1);
            #pragma unroll
            for (int nt = 0; nt < 4; ++nt) {
                bf16x8 vb0 = *(const bf16x8*)&Vts[(nt * 16 + lr) * PSTR + quad * 8];
                bf16x8 vb1 = *(const bf16x8*)&Vts[(nt * 16 + lr) * PSTR + 32 + quad * 8];
                acc[nt] = __builtin_amdgcn_mfma_f32_16x16x32_bf16(pa0, vb0, acc[nt], 0, 0, 0);
                acc[nt] = __builtin_amdgcn_mfma_f32_16x16x32_bf16(pa1, vb1, acc[nt], 0, 0, 0);
            }
            __builtin_amdgcn_s_setprio(0);

            if (havenext) {
                __syncthreads();   // all reads of Ks/Vts done before overwrite
                *(uint4*)&Ks[srow * PSTR + scb]      = kr0;
                *(uint4*)&Ks[srow * PSTR + scb + 8]  = kr1;
                *(uint4*)&Vts[srow * PSTR + scb]     = vr0;
                *(uint4*)&Vts[srow * PSTR + scb + 8] = vr1;
                __syncthreads();   // new tile visible
            }
        }

        // epilogue: reduce l across the 16 lanes of each row group, write ctx
        #pragma unroll
        for (int r = 0; r < 4; ++r) {
            float l = l_loc[r];
            #pragma unroll
            for (int off = 1; off < 16; off <<= 1) l += __shfl_xor(l, off);
            const float invl = (l > 0.f) ? (1.0f / l) : 0.f;
            const int qrow = prow + r;
            #pragma unroll
            for (int nt = 0; nt < 4; ++nt) {
                ctx[(size_t)(b * T_ + qs + qrow) * D_ + hh * DH + nt * 16 + lr] =
                    f2bf(acc[nt][r] * invl);
            }
        }
    }
}

// ---------------------------------------------------------------- launch
extern "C" void kernel_launch(void* const* d_in, const int* in_sizes, int n_in,
                              void* d_out, int out_size, void* d_ws, size_t ws_size,
                              hipStream_t stream) {
    // ws layout: [h][q][k][vt : 16MB each][wtq|wtk|wtv|wto : 2MB each]
    //            [vtmp 16MB][rope table 512KB][work-queue counter 64B]
    u16* h = (u16*)d_ws;
    const size_t MD = (size_t)M_ * D_;
    const size_t WD = (size_t)D_ * D_;
    u16* q  = h + MD;
    u16* k  = q + MD;
    u16* vt = k + MD;
    const bool havewt  = ws_size >= (4 * MD + 4 * WD) * sizeof(u16);
    const bool havebig = ws_size >= (5 * MD + 4 * WD) * sizeof(u16)
                                    + (size_t)T_ * 32 * sizeof(float2) + 64;
    u16* wtq = havewt ? (vt + MD)  : nullptr;
    u16* wtk = havewt ? (wtq + WD) : nullptr;
    u16* wtv = havewt ? (wtk + WD) : nullptr;
    u16* wto = havewt ? (wtv + WD) : nullptr;
    u16* vtmp = havebig ? (wto + WD) : nullptr;
    float2* tab = havebig ? (float2*)(vtmp + MD) : nullptr;
    u32* ctr = havebig ? (u32*)(tab + (size_t)T_ * 32) : nullptr;

    if (havebig) {
        // fused ln + weight-transpose + rope table (+ queue reset)
        prep_kernel<<<M_ + 1024 + 256, 256, 0, stream>>>(
            d_in[0], d_in[1], d_in[2], h,
            d_in[3], d_in[5], d_in[7], d_in[9], wtq, wtk, wtv, wto, tab, ctr);

        qkv256_kernel<<<384, 512, 0, stream>>>(
            h, wtq, d_in[3], d_in[4], d_in[6], d_in[8], q, k, vtmp, tab);

        vtrans_kernel<<<dim3(T_ / 64, NB * H_), 256, 0, stream>>>(vtmp, vt);

        attn_kernel<<<1024, 256, 0, stream>>>(q, k, vt, d_in[13], h, ctr, 1);

        gemm128_kernel<<<8 * (M_ / 128), 256, 0, stream>>>(
            h, wto, d_in[9], d_in[10], d_out, 8, 0);
    } else if (havewt) {
        // fallback: separate kernels, scatter epilogues, static attn mapping
        prep_kernel<<<M_, 256, 0, stream>>>(
            d_in[0], d_in[1], d_in[2], h,
            d_in[3], d_in[5], d_in[7], d_in[9], wtq, wtk, wtv, wto, nullptr, nullptr);
        dim3 wgrid(D_ / 64, D_ / 64);
        wconv_kernel<<<wgrid, 256, 0, stream>>>(d_in[3], wtq);
        wconv_kernel<<<wgrid, 256, 0, stream>>>(d_in[5], wtk);
        wconv_kernel<<<wgrid, 256, 0, stream>>>(d_in[7], wtv);
        wconv_kernel<<<wgrid, 256, 0, stream>>>(d_in[9], wto);

        const int g1 = 8 * (M_ / 128);
        gemm128_kernel<<<g1, 256, 0, stream>>>(h, wtq, d_in[3], d_in[4], q, 8, 2);
        gemm128_kernel<<<g1, 256, 0, stream>>>(h, wtk, d_in[5], d_in[6], k, 8, 2);
        gemm128_kernel<<<g1, 256, 0, stream>>>(h, wtv, d_in[7], d_in[8], vt, 8, 1);

        attn_kernel<<<NB * H_ * 32, 256, 0, stream>>>(q, k, vt, d_in[13], h, nullptr, 0);

        gemm128_kernel<<<g1, 256, 0, stream>>>(h, wto, d_in[9], d_in[10], d_out, 8, 0);
    } else {
        prep_kernel<<<M_, 256, 0, stream>>>(
            d_in[0], d_in[1], d_in[2], h,
            d_in[3], d_in[5], d_in[7], d_in[9], nullptr, nullptr, nullptr, nullptr, nullptr, nullptr);
        dim3 ggrid(D_ / 64, M_ / 128);
        gemm_kernel<<<ggrid, 256, 0, stream>>>(h, d_in[3], d_in[4], q, 2);
        gemm_kernel<<<ggrid, 256, 0, stream>>>(h, d_in[5], d_in[6], k, 2);
        gemm_kernel<<<ggrid, 256, 0, stream>>>(h, d_in[7], d_in[8], vt, 1);

        attn_kernel<<<NB * H_ * 32, 256, 0, stream>>>(q, k, vt, d_in[13], h, nullptr, 0);

        gemm_kernel<<<ggrid, 256, 0, stream>>>(h, d_in[9], d_in[10], d_out, 0);
    }
}

// Round 9
// 366.216 us; speedup vs baseline: 1.0852x; 1.0852x over previous
//
#include <hip/hip_runtime.h>
#include <hip/hip_bf16.h>

typedef unsigned short u16;
typedef unsigned int   u32;
typedef __bf16 bf16x8 __attribute__((ext_vector_type(8)));
typedef float  f32x4  __attribute__((ext_vector_type(4)));

#define NB 4
#define T_ 2048
#define D_ 1024
#define H_ 16
#define DH 64
#define M_ (NB * T_)   // 8192 rows
#define PSTR 72        // padded LDS row stride (elements) for 64-wide tiles

__device__ __forceinline__ float bf2f(u16 u) {
    union { u32 i; float f; } v; v.i = ((u32)u) << 16; return v.f;
}
// manual RTNE round (compiler folds to ~3-4 VALU ops via v_add3)
__device__ __forceinline__ u16 f2bf(float f) {
    union { float fl; u32 i; } v; v.fl = f;
    u32 r = v.i + 0x7fff + ((v.i >> 16) & 1);
    return (u16)(r >> 16);
}

// async global->LDS, 16B per lane; lds base must be wave-uniform
__device__ __forceinline__ void gl_lds16(const u16* g, u16* l) {
    __builtin_amdgcn_global_load_lds((const __attribute__((address_space(1))) void*)g,
                                     (__attribute__((address_space(3))) void*)l,
                                     16, 0, 0);
}

// ---------------------------------------------------------- dtype detector
__device__ __forceinline__ int detect_f32(const u16* p) {
    int weird = 0;
    const int lane = threadIdx.x & 63;
    #pragma unroll
    for (int i = 0; i < 4; ++i) {
        const u16 u = p[lane * 4 + i];
        const int e = (u >> 7) & 0xFF;
        weird += (e == 0xFF || (e >= 0x01 && e <= 0x3F) || (e >= 0xC0 && e <= 0xFE));
    }
    #pragma unroll
    for (int off = 32; off; off >>= 1) weird += __shfl_xor(weird, off);
    return weird >= 16;
}

// int32/int64-tolerant sequence-length read
__device__ __forceinline__ int read_len(const void* raw, int b) {
    const int* a32 = (const int*)raw;
    bool ok32 = true;
    #pragma unroll
    for (int i = 0; i < NB; ++i) {
        const int v = a32[i];
        if (v < 1 || v > T_) ok32 = false;
    }
    int v = ok32 ? a32[b] : (int)((const long long*)raw)[b];
    return min(max(v, 1), T_);
}

// ---------------------------------------------------------------- fused prep
// blocks [0, 8192)            : LayerNorm rows
// blocks [8192, 8192+1024)    : weight transpose tiles (4 weights x 256 tiles)
// blocks [9216, 9216+256)     : RoPE cos/sin table (+ work-queue counter reset)
__global__ __launch_bounds__(256) void prep_kernel(const void* __restrict__ xraw,
                                                   const void* __restrict__ graw,
                                                   const void* __restrict__ braw,
                                                   u16* __restrict__ h,
                                                   const void* __restrict__ W0,
                                                   const void* __restrict__ W1,
                                                   const void* __restrict__ W2,
                                                   const void* __restrict__ W3,
                                                   u16* __restrict__ Wt0,
                                                   u16* __restrict__ Wt1,
                                                   u16* __restrict__ Wt2,
                                                   u16* __restrict__ Wt3,
                                                   float2* __restrict__ tab,
                                                   u32* __restrict__ ctr) {
    __shared__ __align__(16) u16 sh[64 * PSTR];
    const int bid = blockIdx.x;
    const int tid = threadIdx.x;

    if (bid < M_) {
        // ---- LayerNorm ----
        const int row = bid;
        const int isf = detect_f32((const u16*)xraw);
        float* red = (float*)sh;

        float xv[4];
        if (isf) {
            const float* xr = (const float*)xraw + (size_t)row * D_;
            *(float4*)xv = *(const float4*)&xr[tid * 4];
        } else {
            const u16* xr = (const u16*)xraw + (size_t)row * D_;
            u16 loc[4] __attribute__((aligned(8)));
            *(uint2*)loc = *(const uint2*)&xr[tid * 4];
            #pragma unroll
            for (int i = 0; i < 4; ++i) xv[i] = bf2f(loc[i]);
        }

        float s = xv[0] + xv[1] + xv[2] + xv[3];
        float q = xv[0]*xv[0] + xv[1]*xv[1] + xv[2]*xv[2] + xv[3]*xv[3];
        #pragma unroll
        for (int off = 32; off; off >>= 1) {
            s += __shfl_xor(s, off);
            q += __shfl_xor(q, off);
        }
        const int wave = tid >> 6, lane = tid & 63;
        if (lane == 0) { red[wave] = s; red[4 + wave] = q; }
        __syncthreads();
        s = red[0] + red[1] + red[2] + red[3];
        q = red[4] + red[5] + red[6] + red[7];

        const float mean = s * (1.0f / D_);
        const float var  = q * (1.0f / D_) - mean * mean;
        const float rs   = rsqrtf(var + 1e-5f);

        u16 o[4] __attribute__((aligned(8)));
        #pragma unroll
        for (int i = 0; i < 4; ++i) {
            const int c = tid * 4 + i;
            const float gv = isf ? ((const float*)graw)[c] : bf2f(((const u16*)graw)[c]);
            const float bv = isf ? ((const float*)braw)[c] : bf2f(((const u16*)braw)[c]);
            o[i] = f2bf((xv[i] - mean) * rs * gv + bv);
        }
        *(uint2*)&h[(size_t)row * D_ + tid * 4] = *(uint2*)o;
    } else if (bid < M_ + 1024) {
        // ---- weight transpose+convert ----
        const int w = bid - M_;
        const int z = w >> 8;            // weight index 0..3
        const int t = w & 255;
        const void* Wraw = (z == 0) ? W0 : (z == 1) ? W1 : (z == 2) ? W2 : W3;
        u16* Wt          = (z == 0) ? Wt0 : (z == 1) ? Wt1 : (z == 2) ? Wt2 : Wt3;
        u16 (*tile)[PSTR] = (u16(*)[PSTR])sh;
        const int isf = detect_f32((const u16*)Wraw);
        const int n0 = (t & 15) * 64;
        const int k0 = (t >> 4) * 64;
        const int tr  = tid >> 2;          // 0..63
        const int tc  = (tid & 3) * 16;    // 0,16,32,48

        if (isf) {
            const float* W = (const float*)Wraw;
            #pragma unroll
            for (int i = 0; i < 16; ++i)
                tile[tc + i][tr] = f2bf(W[(size_t)(k0 + tr) * D_ + n0 + tc + i]);
        } else {
            const u16* W = (const u16*)Wraw;
            #pragma unroll
            for (int i = 0; i < 16; ++i)
                tile[tc + i][tr] = W[(size_t)(k0 + tr) * D_ + n0 + tc + i];
        }
        __syncthreads();
        *(uint4*)&Wt[(size_t)(n0 + tr) * D_ + k0 + tc]     = *(uint4*)&tile[tr][tc];
        *(uint4*)&Wt[(size_t)(n0 + tr) * D_ + k0 + tc + 8] = *(uint4*)&tile[tr][tc + 8];
    } else {
        // ---- RoPE table: tab[t*32+i] = {cos, sin}(t * 10000^(-i/32)) ----
        const int gid = (bid - (M_ + 1024)) * 256 + tid;  // 0..65535
        if (gid == 0 && ctr) ctr[0] = 0;                  // reset attn work queue
        const int t = gid >> 5, i = gid & 31;
        const float inv = exp2f(-(float)i * 0.41524101186092f);
        const float ang = (float)t * inv;
        float sv, cv;
        sincosf(ang, &sv, &cv);
        tab[gid] = make_float2(cv, sv);
    }
}

// single-weight transpose (fallback path)
__global__ __launch_bounds__(256) void wconv_kernel(const void* __restrict__ Wraw,
                                                    u16* __restrict__ Wt) {
    __shared__ u16 tile[64][PSTR];
    const int isf = detect_f32((const u16*)Wraw);
    const int n0 = blockIdx.x * 64;
    const int k0 = blockIdx.y * 64;
    const int tid = threadIdx.x;
    const int tr  = tid >> 2;
    const int tc  = (tid & 3) * 16;

    if (isf) {
        const float* W = (const float*)Wraw;
        #pragma unroll
        for (int i = 0; i < 16; ++i)
            tile[tc + i][tr] = f2bf(W[(size_t)(k0 + tr) * D_ + n0 + tc + i]);
    } else {
        const u16* W = (const u16*)Wraw;
        #pragma unroll
        for (int i = 0; i < 16; ++i)
            tile[tc + i][tr] = W[(size_t)(k0 + tr) * D_ + n0 + tc + i];
    }
    __syncthreads();
    *(uint4*)&Wt[(size_t)(n0 + tr) * D_ + k0 + tc]     = *(uint4*)&tile[tr][tc];
    *(uint4*)&Wt[(size_t)(n0 + tr) * D_ + k0 + tc + 8] = *(uint4*)&tile[tr][tc + 8];
}

// --------------------------------------------------- V transpose (per head)
// vtmp (M, D) row-major -> vt (N, H, DH, T)
__global__ __launch_bounds__(256) void vtrans_kernel(const u16* __restrict__ vtmp,
                                                     u16* __restrict__ vt) {
    __shared__ u16 tile[64][PSTR];
    const int bh = blockIdx.y;
    const int b  = bh >> 4;
    const int hh = bh & 15;
    const int t0 = blockIdx.x * 64;
    const int tid = threadIdx.x;
    const int tr  = tid >> 2;          // 0..63
    const int tc  = (tid & 3) * 16;

    #pragma unroll
    for (int i = 0; i < 16; ++i)   // tile[d][t]
        tile[tc + i][tr] = vtmp[(size_t)(b * T_ + t0 + tr) * D_ + hh * DH + tc + i];
    __syncthreads();
    u16* dst = vt + (size_t)bh * DH * T_ + (size_t)tr * T_ + t0;
    *(uint4*)&dst[tc]     = *(uint4*)&tile[tr][tc];
    *(uint4*)&dst[tc + 8] = *(uint4*)&tile[tr][tc + 8];
}

// ---------------------------------------------------------------- fused QKV GEMM
// 128x128 tile, BK=64, XOR-swizzled LDS (R7 layout: 0 bank conflicts) +
// DOUBLE-buffered with stage-next-FIRST, ONE barrier per K-step (its implicit
// vmcnt(0) drain lands loads that had the whole compute phase in flight).
// LDS 64KB -> 2 blocks/CU; grid 1536 = 6/CU -> 3 balanced rounds of 2.
// Outputs ROW-MAJOR (M, D); Q,K: table RoPE.
__global__ __launch_bounds__(256) void qkv_kernel(const u16* __restrict__ A,
                                                  const u16* __restrict__ Wt3,
                                                  const void* __restrict__ Braw,
                                                  const void* __restrict__ bqr,
                                                  const void* __restrict__ bkr,
                                                  const void* __restrict__ bvr,
                                                  u16* __restrict__ qo,
                                                  u16* __restrict__ ko,
                                                  u16* __restrict__ vo,
                                                  const float2* __restrict__ tab) {
    __shared__ __align__(16) u16 As[2][128 * 64];
    __shared__ __align__(16) u16 Bs[2][128 * 64];

    const int tid   = threadIdx.x;
    const int wave  = tid >> 6;
    const int lane  = tid & 63;
    const int quad  = lane >> 4;
    const int lr    = lane & 15;

    // chunked XCD swizzle: 1536 = 8 * 192
    const int bid = blockIdx.x;
    const int wg  = (bid & 7) * 192 + (bid >> 3);
    const int ntile = (wg % 24) * 128;       // 0..2944
    const int mtile = (wg / 24) * 128;
    const int seg   = ntile >> 10;           // 0=Q 1=K 2=V

    const int isf = detect_f32((const u16*)Braw);

    // staging: wave w, issue j covers rows w*8 + j*32 .. +7 (row&7 == lane>>3)
    // pre-swizzled source column chunk: (lane&7) ^ (lane>>3)  (G21 both-sides)
    const int srow = wave * 8 + (lane >> 3);
    const int sc   = (((lane & 7) ^ (lane >> 3)) * 8);
    const u16* aP = A   + (size_t)(mtile + srow) * D_ + sc;
    const u16* bP = Wt3 + (size_t)(ntile + srow) * D_ + sc;
    const int lofs = (wave * 8) * 64;        // wave-uniform LDS offset (in-buf)

    const int mbase = (wave >> 1) * 64;
    const int nbase = (wave & 1) * 64;

    f32x4 acc[4][4];
    #pragma unroll
    for (int m = 0; m < 4; ++m)
        #pragma unroll
        for (int n = 0; n < 4; ++n)
            acc[m][n] = (f32x4){0.f, 0.f, 0.f, 0.f};

    // prologue: stage K-tile 0 into buf 0
    #pragma unroll
    for (int j = 0; j < 4; ++j) {
        gl_lds16(aP + (size_t)(j * 32) * D_, &As[0][lofs + (j * 32) * 64]);
        gl_lds16(bP + (size_t)(j * 32) * D_, &Bs[0][lofs + (j * 32) * 64]);
    }
    __syncthreads();

    int cur = 0;
    for (int kk = 0; kk < D_ / 64; ++kk) {
        const int nxt = cur ^ 1;
        if (kk + 1 < D_ / 64) {
            const int k0 = (kk + 1) * 64;
            #pragma unroll
            for (int j = 0; j < 4; ++j) {
                gl_lds16(aP + (size_t)(j * 32) * D_ + k0, &As[nxt][lofs + (j * 32) * 64]);
                gl_lds16(bP + (size_t)(j * 32) * D_ + k0, &Bs[nxt][lofs + (j * 32) * 64]);
            }
        }

        #pragma unroll
        for (int c = 0; c < 2; ++c) {
            bf16x8 af[4], bfr[4];
            #pragma unroll
            for (int m = 0; m < 4; ++m) {
                const int row = mbase + m * 16 + lr;
                af[m] = *(const bf16x8*)&As[cur][row * 64 + (((c << 2) | quad) ^ (row & 7)) * 8];
            }
            #pragma unroll
            for (int n = 0; n < 4; ++n) {
                const int row = nbase + n * 16 + lr;
                bfr[n] = *(const bf16x8*)&Bs[cur][row * 64 + (((c << 2) | quad) ^ (row & 7)) * 8];
            }
            __builtin_amdgcn_s_setprio(1);
            #pragma unroll
            for (int m = 0; m < 4; ++m)
                #pragma unroll
                for (int n = 0; n < 4; ++n)
                    acc[m][n] = __builtin_amdgcn_mfma_f32_16x16x32_bf16(af[m], bfr[n], acc[m][n], 0, 0, 0);
            __builtin_amdgcn_s_setprio(0);
        }

        __syncthreads();   // drains vmcnt(0): staged nxt ready; cur reads done
        cur = nxt;
    }

    const void* biasraw = (seg == 0) ? bqr : (seg == 1) ? bkr : bvr;
    u16* out            = (seg == 0) ? qo  : (seg == 1) ? ko  : vo;
    const int nloc = (ntile & 1023) + nbase;

    #pragma unroll
    for (int m = 0; m < 4; ++m) {
        #pragma unroll
        for (int n = 0; n < 4; ++n) {
            const int ncl = nloc + n * 16 + lr;       // 0..1023 within segment
            const float bv = isf ? ((const float*)biasraw)[ncl]
                                 : bf2f(((const u16*)biasraw)[ncl]);
            #pragma unroll
            for (int r = 0; r < 4; ++r) {
                const int mrow = mtile + mbase + m * 16 + quad * 4 + r;
                float v = acc[m][n][r] + bv;
                if (seg < 2) {
                    const float other = __shfl_xor(v, 1);
                    const int d = ncl & (DH - 1);
                    const int t = mrow & (T_ - 1);
                    const float2 cs = tab[t * 32 + (d >> 1)];
                    v = (d & 1) ? (other * cs.y + v * cs.x) : (v * cs.x - other * cs.y);
                }
                out[(size_t)mrow * D_ + ncl] = f2bf(v);
            }
        }
    }
}

// ---------------------------------------------------------------- GEMM (BK=64 swizzled dbuf)
// Same structure as qkv_kernel. nwg = nx * 64, divisible by 8.
// mode 0: row-major store; mode 1: V-transposed scatter; mode 2: RoPE scatter
__global__ __launch_bounds__(256) void gemm128_kernel(const u16* __restrict__ A,
                                                      const u16* __restrict__ Bt,
                                                      const void* __restrict__ Braw,
                                                      const void* __restrict__ biasraw,
                                                      void* __restrict__ out,
                                                      const int nx,
                                                      const int mode) {
    __shared__ __align__(16) u16 As[2][128 * 64];
    __shared__ __align__(16) u16 Bs[2][128 * 64];

    const int tid   = threadIdx.x;
    const int wave  = tid >> 6;
    const int lane  = tid & 63;
    const int quad  = lane >> 4;
    const int lr    = lane & 15;

    const int bid = blockIdx.x;
    const int cpx = (nx * (M_ / 128)) >> 3;
    const int wg  = (bid & 7) * cpx + (bid >> 3);
    const int ntile = (wg % nx) * 128;
    const int mtile = (wg / nx) * 128;

    const int isf = detect_f32((const u16*)Braw);

    const int srow = wave * 8 + (lane >> 3);
    const int sc   = (((lane & 7) ^ (lane >> 3)) * 8);
    const u16* aP = A  + (size_t)(mtile + srow) * D_ + sc;
    const u16* bP = Bt + (size_t)(ntile + srow) * D_ + sc;
    const int lofs = (wave * 8) * 64;

    const int mbase = (wave >> 1) * 64;
    const int nbase = (wave & 1) * 64;

    f32x4 acc[4][4];
    #pragma unroll
    for (int m = 0; m < 4; ++m)
        #pragma unroll
        for (int n = 0; n < 4; ++n)
            acc[m][n] = (f32x4){0.f, 0.f, 0.f, 0.f};

    #pragma unroll
    for (int j = 0; j < 4; ++j) {
        gl_lds16(aP + (size_t)(j * 32) * D_, &As[0][lofs + (j * 32) * 64]);
        gl_lds16(bP + (size_t)(j * 32) * D_, &Bs[0][lofs + (j * 32) * 64]);
    }
    __syncthreads();

    int cur = 0;
    for (int kk = 0; kk < D_ / 64; ++kk) {
        const int nxt = cur ^ 1;
        if (kk + 1 < D_ / 64) {
            const int k0 = (kk + 1) * 64;
            #pragma unroll
            for (int j = 0; j < 4; ++j) {
                gl_lds16(aP + (size_t)(j * 32) * D_ + k0, &As[nxt][lofs + (j * 32) * 64]);
                gl_lds16(bP + (size_t)(j * 32) * D_ + k0, &Bs[nxt][lofs + (j * 32) * 64]);
            }
        }

        #pragma unroll
        for (int c = 0; c < 2; ++c) {
            bf16x8 af[4], bfr[4];
            #pragma unroll
            for (int m = 0; m < 4; ++m) {
                const int row = mbase + m * 16 + lr;
                af[m] = *(const bf16x8*)&As[cur][row * 64 + (((c << 2) | quad) ^ (row & 7)) * 8];
            }
            #pragma unroll
            for (int n = 0; n < 4; ++n) {
                const int row = nbase + n * 16 + lr;
                bfr[n] = *(const bf16x8*)&Bs[cur][row * 64 + (((c << 2) | quad) ^ (row & 7)) * 8];
            }
            __builtin_amdgcn_s_setprio(1);
            #pragma unroll
            for (int m = 0; m < 4; ++m)
                #pragma unroll
                for (int n = 0; n < 4; ++n)
                    acc[m][n] = __builtin_amdgcn_mfma_f32_16x16x32_bf16(af[m], bfr[n], acc[m][n], 0, 0, 0);
            __builtin_amdgcn_s_setprio(0);
        }

        __syncthreads();
        cur = nxt;
    }

    #pragma unroll
    for (int m = 0; m < 4; ++m) {
        #pragma unroll
        for (int n = 0; n < 4; ++n) {
            const int ncol = ntile + nbase + n * 16 + lr;
            const float bv = isf ? ((const float*)biasraw)[ncol]
                                 : bf2f(((const u16*)biasraw)[ncol]);
            #pragma unroll
            for (int r = 0; r < 4; ++r) {
                const int mrow = mtile + mbase + m * 16 + quad * 4 + r;
                float v = acc[m][n][r] + bv;
                if (mode == 2) {
                    const float other = __shfl_xor(v, 1);
                    const int d = ncol & (DH - 1);
                    const int t = mrow & (T_ - 1);
                    const int i = d >> 1;
                    const float inv = exp2f(-(float)i * 0.41524101186092f);
                    const float ang = (float)t * inv;
                    float sv, cv;
                    __sincosf(ang, &sv, &cv);
                    v = (d & 1) ? (other * sv + v * cv) : (v * cv - other * sv);
                }
                const int d  = ncol & (DH - 1);
                const int hh = ncol >> 6;
                const int t  = mrow & (T_ - 1);
                const int bb = mrow >> 11;
                if (mode == 0) {
                    if (isf) ((float*)out)[(size_t)mrow * D_ + ncol] = v;
                    else     ((u16*)out)[(size_t)mrow * D_ + ncol] = f2bf(v);
                } else if (mode == 1) {
                    ((u16*)out)[(((size_t)(bb * H_ + hh) * DH) + d) * T_ + t] = f2bf(v);
                } else {
                    ((u16*)out)[(((size_t)(bb * H_ + hh) * T_) + t) * DH + d] = f2bf(v);
                }
            }
        }
    }
}

// ---------------------------------------------------------------- GEMM (no-wt fallback)
__global__ __launch_bounds__(256) void gemm_kernel(const u16* __restrict__ A,
                                                   const void* __restrict__ Braw,
                                                   const void* __restrict__ biasraw,
                                                   void* __restrict__ out,
                                                   const int mode) {
    __shared__ __align__(16) u16 As[128 * 32];
    __shared__ __align__(16) u16 Bs[64 * 32];

    const int tid   = threadIdx.x;
    const int ntile = blockIdx.x * 64;
    const int mtile = blockIdx.y * 128;
    const int wave  = tid >> 6;
    const int lane  = tid & 63;
    const int quad  = lane >> 4;
    const int lr    = lane & 15;

    const int isf = detect_f32((const u16*)Braw);
    const float* Bf = (const float*)Braw;
    const u16*   Bu = (const u16*)Braw;

    f32x4 acc[2][4];
    #pragma unroll
    for (int s = 0; s < 2; ++s)
        #pragma unroll
        for (int n = 0; n < 4; ++n)
            acc[s][n] = (f32x4){0.f, 0.f, 0.f, 0.f};

    const int ar  = tid >> 1;
    const int akb = (tid & 1) * 16;
    const int bn  = tid & 63;
    const int bkb = (tid >> 6) * 8;
    const u16* Arow = A + (size_t)(mtile + ar) * D_ + akb;
    const size_t bcol0 = (size_t)bkb * D_ + ntile + bn;

    for (int k0 = 0; k0 < D_; k0 += 32) {
        *(uint4*)&As[ar * 32 + akb]     = *(const uint4*)(Arow + k0);
        *(uint4*)&As[ar * 32 + akb + 8] = *(const uint4*)(Arow + k0 + 8);
        {
            u16 tmp[8] __attribute__((aligned(16)));
            if (isf) {
                #pragma unroll
                for (int j = 0; j < 8; ++j) tmp[j] = f2bf(Bf[bcol0 + (size_t)(k0 + j) * D_]);
            } else {
                #pragma unroll
                for (int j = 0; j < 8; ++j) tmp[j] = Bu[bcol0 + (size_t)(k0 + j) * D_];
            }
            *(uint4*)&Bs[bn * 32 + bkb] = *(uint4*)tmp;
        }
        __syncthreads();

        const int mbase = wave * 32;
        bf16x8 af0 = *(const bf16x8*)&As[(mbase +      lr) * 32 + quad * 8];
        bf16x8 af1 = *(const bf16x8*)&As[(mbase + 16 + lr) * 32 + quad * 8];
        #pragma unroll
        for (int nt = 0; nt < 4; ++nt) {
            bf16x8 bf = *(const bf16x8*)&Bs[(nt * 16 + lr) * 32 + quad * 8];
            acc[0][nt] = __builtin_amdgcn_mfma_f32_16x16x32_bf16(af0, bf, acc[0][nt], 0, 0, 0);
            acc[1][nt] = __builtin_amdgcn_mfma_f32_16x16x32_bf16(af1, bf, acc[1][nt], 0, 0, 0);
        }
        __syncthreads();
    }

    #pragma unroll
    for (int s2 = 0; s2 < 2; ++s2) {
        #pragma unroll
        for (int nt = 0; nt < 4; ++nt) {
            const int ncol = ntile + nt * 16 + lr;
            const float bv = isf ? ((const float*)biasraw)[ncol]
                                 : bf2f(((const u16*)biasraw)[ncol]);
            #pragma unroll
            for (int r = 0; r < 4; ++r) {
                const int mrow = mtile + wave * 32 + s2 * 16 + quad * 4 + r;
                float v = acc[s2][nt][r] + bv;
                if (mode == 2) {
                    const float other = __shfl_xor(v, 1);
                    const int d = ncol & (DH - 1);
                    const int t = mrow & (T_ - 1);
                    const int i = d >> 1;
                    const float inv = exp2f(-(float)i * 0.41524101186092f);
                    const float ang = (float)t * inv;
                    const float cv = cosf(ang), sv = sinf(ang);
                    v = (d & 1) ? (other * sv + v * cv) : (v * cv - other * sv);
                }
                const int d  = ncol & (DH - 1);
                const int hh = ncol >> 6;
                const int t  = mrow & (T_ - 1);
                const int bb = mrow >> 11;
                if (mode == 0) {
                    if (isf) ((float*)out)[(size_t)mrow * D_ + ncol] = v;
                    else     ((u16*)out)[(size_t)mrow * D_ + ncol] = f2bf(v);
                } else if (mode == 1) {
                    ((u16*)out)[(((size_t)(bb * H_ + hh) * DH) + d) * T_ + t] = f2bf(v);
                } else {
                    ((u16*)out)[(((size_t)(bb * H_ + hh) * T_) + t) * DH + d] = f2bf(v);
                }
            }
        }
    }
}

// ---------------------------------------------------------------- attention
// Persistent-block work-queue flash attention, FIXED-MAX softmax:
//   p = exp2(C2 * rcp(z+1)), z = exp2(s*C1)   -- raw v_exp/v_rcp only
// Work items = 2048 (bh, q-tile) units ordered q-tile DESCENDING (LPT).
// ctr != nullptr: 1024 persistent blocks pull items via device atomicAdd
// (counter zeroed by prep each replay). ctr == nullptr: item = blockIdx.x.
// Inner loop: reg prefetch, 2 barriers/tile, no-barrier wave-private
// softmax->PV, setprio around MFMA.
// rowmajor=1: Q/K are (M, D); rowmajor=0: (N,H,T,DH).
__global__ __launch_bounds__(256) void attn_kernel(const u16* __restrict__ Q,
                                                   const u16* __restrict__ K,
                                                   const u16* __restrict__ Vt,
                                                   const void* __restrict__ lensraw,
                                                   u16* __restrict__ ctx,
                                                   u32* __restrict__ ctr,
                                                   const int rowmajor) {
    __shared__ __align__(16) u16 Ps[64 * PSTR];    // Q staging, then P tile
    __shared__ __align__(16) u16 Ks[64 * PSTR];
    __shared__ __align__(16) u16 Vts[64 * PSTR];   // [dim][key]
    __shared__ int item_s;

    const int tid  = threadIdx.x;
    const int wave = tid >> 6;
    const int lane = tid & 63;
    const int quad = lane >> 4;
    const int lr   = lane & 15;
    const int srow = tid >> 2;          // wave w covers rows 16w..16w+15
    const int scb  = (tid & 3) * 16;
    const int prow = wave * 16 + quad * 4;

    const float C1 = 1.44269504f / 120.0f;   // log2e / 120
    const float C2 = -60.0f * 1.44269504f;   // -60 * log2e

    for (int iter = 0; ; ++iter) {
        if (tid == 0)
            item_s = ctr ? (int)atomicAdd(ctr, 1u)
                         : (iter == 0 ? (int)blockIdx.x : NB * H_ * 32);
        __syncthreads();   // broadcast; also guards LDS reuse across items
        const int item = item_s;
        if (item >= NB * H_ * 32) break;

        // LPT mapping: longest q-tiles first
        const int qt = 31 - (item >> 6);   // 31..0
        const int bh = item & 63;
        const int qs = qt * 64;
        const int b  = bh >> 4;
        const int hh = bh & 15;
        const int len = read_len(lensraw, b);

        const size_t qkstride = rowmajor ? (size_t)D_ : (size_t)DH;
        const size_t qkoff    = rowmajor ? ((size_t)b * T_ * D_ + hh * DH)
                                         : ((size_t)bh * T_ * DH);
        const u16* Qp = Q + qkoff;
        const u16* Kp = K + qkoff;
        const u16* Vb = Vt + (size_t)bh * DH * T_;

        // Q staging (wave-private rows; no barrier needed) + K/V tile 0
        *(uint4*)&Ps[srow * PSTR + scb]     = *(const uint4*)&Qp[(size_t)(qs + srow) * qkstride + scb];
        *(uint4*)&Ps[srow * PSTR + scb + 8] = *(const uint4*)&Qp[(size_t)(qs + srow) * qkstride + scb + 8];
        const bf16x8 qa0 = *(const bf16x8*)&Ps[(wave * 16 + lr) * PSTR + quad * 8];
        const bf16x8 qa1 = *(const bf16x8*)&Ps[(wave * 16 + lr) * PSTR + 32 + quad * 8];
        {
            uint4 k0 = *(const uint4*)&Kp[(size_t)srow * qkstride + scb];
            uint4 k1 = *(const uint4*)&Kp[(size_t)srow * qkstride + scb + 8];
            uint4 v0 = *(const uint4*)&Vb[(size_t)srow * T_ + scb];
            uint4 v1 = *(const uint4*)&Vb[(size_t)srow * T_ + scb + 8];
            *(uint4*)&Ks[srow * PSTR + scb]      = k0;
            *(uint4*)&Ks[srow * PSTR + scb + 8]  = k1;
            *(uint4*)&Vts[srow * PSTR + scb]     = v0;
            *(uint4*)&Vts[srow * PSTR + scb + 8] = v1;
        }
        __syncthreads();

        f32x4 acc[4];
        float l_loc[4] = {0.f, 0.f, 0.f, 0.f};
        #pragma unroll
        for (int nt = 0; nt < 4; ++nt) acc[nt] = (f32x4){0.f, 0.f, 0.f, 0.f};

        const int ktn = min(qs + 63, len - 1) / 64 + 1;

        uint4 kr0, kr1, vr0, vr1;
        for (int kt = 0; kt < ktn; ++kt) {
            const int ks = kt * 64;
            const bool havenext = (kt + 1 < ktn);   // block-uniform

            if (havenext) {
                const int ns = ks + 64;
                kr0 = *(const uint4*)&Kp[(size_t)(ns + srow) * qkstride + scb];
                kr1 = *(const uint4*)&Kp[(size_t)(ns + srow) * qkstride + scb + 8];
                vr0 = *(const uint4*)&Vb[(size_t)srow * T_ + ns + scb];
                vr1 = *(const uint4*)&Vb[(size_t)srow * T_ + ns + scb + 8];
            }

            // QK^T
            f32x4 s[4];
            #pragma unroll
            for (int nt = 0; nt < 4; ++nt) s[nt] = (f32x4){0.f, 0.f, 0.f, 0.f};
            __builtin_amdgcn_s_setprio(1);
            #pragma unroll
            for (int nt = 0; nt < 4; ++nt) {
                bf16x8 kb0 = *(const bf16x8*)&Ks[(nt * 16 + lr) * PSTR + quad * 8];
                bf16x8 kb1 = *(const bf16x8*)&Ks[(nt * 16 + lr) * PSTR + 32 + quad * 8];
                s[nt] = __builtin_amdgcn_mfma_f32_16x16x32_bf16(qa0, kb0, s[nt], 0, 0, 0);
                s[nt] = __builtin_amdgcn_mfma_f32_16x16x32_bf16(qa1, kb1, s[nt], 0, 0, 0);
            }
            __builtin_amdgcn_s_setprio(0);

            // fixed-max softmax; masking only on diagonal / len-boundary tiles
            const bool need_mask = (ks == qs) || (ks + 63 >= len);
            if (!need_mask) {
                #pragma unroll
                for (int r = 0; r < 4; ++r) {
                    #pragma unroll
                    for (int nt = 0; nt < 4; ++nt) {
                        const float z = __builtin_amdgcn_exp2f(s[nt][r] * C1);
                        const float p = __builtin_amdgcn_exp2f(C2 * __builtin_amdgcn_rcpf(z + 1.0f));
                        l_loc[r] += p;
                        Ps[(prow + r) * PSTR + nt * 16 + lr] = f2bf(p);
                    }
                }
            } else {
                #pragma unroll
                for (int r = 0; r < 4; ++r) {
                    const int trow = qs + prow + r;
                    #pragma unroll
                    for (int nt = 0; nt < 4; ++nt) {
                        const float z = __builtin_amdgcn_exp2f(s[nt][r] * C1);
                        float p = __builtin_amdgcn_exp2f(C2 * __builtin_amdgcn_rcpf(z + 1.0f));
                        const int col = ks + nt * 16 + lr;
                        p = (col > trow || col >= len) ? 0.f : p;
                        l_loc[r] += p;
                        Ps[(prow + r) * PSTR + nt * 16 + lr] = f2bf(p);
                    }
                }
            }
            // no barrier: Ps rows are wave-private

            // PV
            bf16x8 pa0 = *(const bf16x8*)&Ps[(wave * 16 + lr) * PSTR + quad * 8];
            bf16x8 pa1 = *(const bf16x8*)&Ps[(wave * 16 + lr) * PSTR + 32 + quad * 8];
            __builtin_amdgcn_s_setprio(1);
            #pragma unroll
            for (int nt = 0; nt < 4; ++nt) {
                bf16x8 vb0 = *(const bf16x8*)&Vts[(nt * 16 + lr) * PSTR + quad * 8];
                bf16x8 vb1 = *(const bf16x8*)&Vts[(nt * 16 + lr) * PSTR + 32 + quad * 8];
                acc[nt] = __builtin_amdgcn_mfma_f32_16x16x32_bf16(pa0, vb0, acc[nt], 0, 0, 0);
                acc[nt] = __builtin_amdgcn_mfma_f32_16x16x32_bf16(pa1, vb1, acc[nt], 0, 0, 0);
            }
            __builtin_amdgcn_s_setprio(0);

            if (havenext) {
                __syncthreads();   // all reads of Ks/Vts done before overwrite
                *(uint4*)&Ks[srow * PSTR + scb]      = kr0;
                *(uint4*)&Ks[srow * PSTR + scb + 8]  = kr1;
                *(uint4*)&Vts[srow * PSTR + scb]     = vr0;
                *(uint4*)&Vts[srow * PSTR + scb + 8] = vr1;
                __syncthreads();   // new tile visible
            }
        }

        // epilogue: reduce l across the 16 lanes of each row group, write ctx
        #pragma unroll
        for (int r = 0; r < 4; ++r) {
            float l = l_loc[r];
            #pragma unroll
            for (int off = 1; off < 16; off <<= 1) l += __shfl_xor(l, off);
            const float invl = (l > 0.f) ? (1.0f / l) : 0.f;
            const int qrow = prow + r;
            #pragma unroll
            for (int nt = 0; nt < 4; ++nt) {
                ctx[(size_t)(b * T_ + qs + qrow) * D_ + hh * DH + nt * 16 + lr] =
                    f2bf(acc[nt][r] * invl);
            }
        }
    }
}

// ---------------------------------------------------------------- launch
extern "C" void kernel_launch(void* const* d_in, const int* in_sizes, int n_in,
                              void* d_out, int out_size, void* d_ws, size_t ws_size,
                              hipStream_t stream) {
    // ws layout: [h][q][k][vt : 16MB each][wtq|wtk|wtv|wto : 2MB each]
    //            [vtmp 16MB][rope table 512KB][work-queue counter 64B]
    u16* h = (u16*)d_ws;
    const size_t MD = (size_t)M_ * D_;
    const size_t WD = (size_t)D_ * D_;
    u16* q  = h + MD;
    u16* k  = q + MD;
    u16* vt = k + MD;
    const bool havewt  = ws_size >= (4 * MD + 4 * WD) * sizeof(u16);
    const bool havebig = ws_size >= (5 * MD + 4 * WD) * sizeof(u16)
                                    + (size_t)T_ * 32 * sizeof(float2) + 64;
    u16* wtq = havewt ? (vt + MD)  : nullptr;
    u16* wtk = havewt ? (wtq + WD) : nullptr;
    u16* wtv = havewt ? (wtk + WD) : nullptr;
    u16* wto = havewt ? (wtv + WD) : nullptr;
    u16* vtmp = havebig ? (wto + WD) : nullptr;
    float2* tab = havebig ? (float2*)(vtmp + MD) : nullptr;
    u32* ctr = havebig ? (u32*)(tab + (size_t)T_ * 32) : nullptr;

    if (havebig) {
        // fused ln + weight-transpose + rope table (+ queue reset)
        prep_kernel<<<M_ + 1024 + 256, 256, 0, stream>>>(
            d_in[0], d_in[1], d_in[2], h,
            d_in[3], d_in[5], d_in[7], d_in[9], wtq, wtk, wtv, wto, tab, ctr);

        qkv_kernel<<<1536, 256, 0, stream>>>(
            h, wtq, d_in[3], d_in[4], d_in[6], d_in[8], q, k, vtmp, tab);

        vtrans_kernel<<<dim3(T_ / 64, NB * H_), 256, 0, stream>>>(vtmp, vt);

        attn_kernel<<<1024, 256, 0, stream>>>(q, k, vt, d_in[13], h, ctr, 1);

        gemm128_kernel<<<8 * (M_ / 128), 256, 0, stream>>>(
            h, wto, d_in[9], d_in[10], d_out, 8, 0);
    } else if (havewt) {
        // fallback: separate kernels, scatter epilogues, static attn mapping
        prep_kernel<<<M_, 256, 0, stream>>>(
            d_in[0], d_in[1], d_in[2], h,
            d_in[3], d_in[5], d_in[7], d_in[9], wtq, wtk, wtv, wto, nullptr, nullptr);
        dim3 wgrid(D_ / 64, D_ / 64);
        wconv_kernel<<<wgrid, 256, 0, stream>>>(d_in[3], wtq);
        wconv_kernel<<<wgrid, 256, 0, stream>>>(d_in[5], wtk);
        wconv_kernel<<<wgrid, 256, 0, stream>>>(d_in[7], wtv);
        wconv_kernel<<<wgrid, 256, 0, stream>>>(d_in[9], wto);

        const int g1 = 8 * (M_ / 128);
        gemm128_kernel<<<g1, 256, 0, stream>>>(h, wtq, d_in[3], d_in[4], q, 8, 2);
        gemm128_kernel<<<g1, 256, 0, stream>>>(h, wtk, d_in[5], d_in[6], k, 8, 2);
        gemm128_kernel<<<g1, 256, 0, stream>>>(h, wtv, d_in[7], d_in[8], vt, 8, 1);

        attn_kernel<<<NB * H_ * 32, 256, 0, stream>>>(q, k, vt, d_in[13], h, nullptr, 0);

        gemm128_kernel<<<g1, 256, 0, stream>>>(h, wto, d_in[9], d_in[10], d_out, 8, 0);
    } else {
        prep_kernel<<<M_, 256, 0, stream>>>(
            d_in[0], d_in[1], d_in[2], h,
            d_in[3], d_in[5], d_in[7], d_in[9], nullptr, nullptr, nullptr, nullptr, nullptr, nullptr);
        dim3 ggrid(D_ / 64, M_ / 128);
        gemm_kernel<<<ggrid, 256, 0, stream>>>(h, d_in[3], d_in[4], q, 2);
        gemm_kernel<<<ggrid, 256, 0, stream>>>(h, d_in[5], d_in[6], k, 2);
        gemm_kernel<<<ggrid, 256, 0, stream>>>(h, d_in[7], d_in[8], vt, 1);

        attn_kernel<<<NB * H_ * 32, 256, 0, stream>>>(q, k, vt, d_in[13], h, nullptr, 0);

        gemm_kernel<<<ggrid, 256, 0, stream>>>(h, d_in[9], d_in[10], d_out, 0);
    }
}

// Round 11
// 350.150 us; speedup vs baseline: 1.1350x; 1.0459x over previous
//
#include <hip/hip_runtime.h>
#include <hip/hip_bf16.h>

typedef unsigned short u16;
typedef unsigned int   u32;
typedef __bf16 bf16x8 __attribute__((ext_vector_type(8)));
typedef float  f32x4  __attribute__((ext_vector_type(4)));

#define NB 4
#define T_ 2048
#define D_ 1024
#define H_ 16
#define DH 64
#define M_ (NB * T_)   // 8192 rows
#define PSTR 72        // padded LDS row stride (elements) for 64-wide tiles

__device__ __forceinline__ float bf2f(u16 u) {
    union { u32 i; float f; } v; v.i = ((u32)u) << 16; return v.f;
}
// manual RTNE round (compiler folds to ~3-4 VALU ops via v_add3)
__device__ __forceinline__ u16 f2bf(float f) {
    union { float fl; u32 i; } v; v.fl = f;
    u32 r = v.i + 0x7fff + ((v.i >> 16) & 1);
    return (u16)(r >> 16);
}

// async global->LDS, 16B per lane; lds base must be wave-uniform
__device__ __forceinline__ void gl_lds16(const u16* g, u16* l) {
    __builtin_amdgcn_global_load_lds((const __attribute__((address_space(1))) void*)g,
                                     (__attribute__((address_space(3))) void*)l,
                                     16, 0, 0);
}

// ---------------------------------------------------------- dtype detector
__device__ __forceinline__ int detect_f32(const u16* p) {
    int weird = 0;
    const int lane = threadIdx.x & 63;
    #pragma unroll
    for (int i = 0; i < 4; ++i) {
        const u16 u = p[lane * 4 + i];
        const int e = (u >> 7) & 0xFF;
        weird += (e == 0xFF || (e >= 0x01 && e <= 0x3F) || (e >= 0xC0 && e <= 0xFE));
    }
    #pragma unroll
    for (int off = 32; off; off >>= 1) weird += __shfl_xor(weird, off);
    return weird >= 16;
}

// int32/int64-tolerant sequence-length read
__device__ __forceinline__ int read_len(const void* raw, int b) {
    const int* a32 = (const int*)raw;
    bool ok32 = true;
    #pragma unroll
    for (int i = 0; i < NB; ++i) {
        const int v = a32[i];
        if (v < 1 || v > T_) ok32 = false;
    }
    int v = ok32 ? a32[b] : (int)((const long long*)raw)[b];
    return min(max(v, 1), T_);
}

// ---------------------------------------------------------------- fused prep
// blocks [0, 8192)            : LayerNorm rows
// blocks [8192, 8192+1024)    : weight transpose tiles (4 weights x 256 tiles)
// blocks [9216, 9216+256)     : RoPE cos/sin table (+ work-queue counter reset)
__global__ __launch_bounds__(256) void prep_kernel(const void* __restrict__ xraw,
                                                   const void* __restrict__ graw,
                                                   const void* __restrict__ braw,
                                                   u16* __restrict__ h,
                                                   const void* __restrict__ W0,
                                                   const void* __restrict__ W1,
                                                   const void* __restrict__ W2,
                                                   const void* __restrict__ W3,
                                                   u16* __restrict__ Wt0,
                                                   u16* __restrict__ Wt1,
                                                   u16* __restrict__ Wt2,
                                                   u16* __restrict__ Wt3,
                                                   float2* __restrict__ tab,
                                                   u32* __restrict__ ctr) {
    __shared__ __align__(16) u16 sh[64 * PSTR];
    const int bid = blockIdx.x;
    const int tid = threadIdx.x;

    if (bid < M_) {
        // ---- LayerNorm ----
        const int row = bid;
        const int isf = detect_f32((const u16*)xraw);
        float* red = (float*)sh;

        float xv[4];
        if (isf) {
            const float* xr = (const float*)xraw + (size_t)row * D_;
            *(float4*)xv = *(const float4*)&xr[tid * 4];
        } else {
            const u16* xr = (const u16*)xraw + (size_t)row * D_;
            u16 loc[4] __attribute__((aligned(8)));
            *(uint2*)loc = *(const uint2*)&xr[tid * 4];
            #pragma unroll
            for (int i = 0; i < 4; ++i) xv[i] = bf2f(loc[i]);
        }

        float s = xv[0] + xv[1] + xv[2] + xv[3];
        float q = xv[0]*xv[0] + xv[1]*xv[1] + xv[2]*xv[2] + xv[3]*xv[3];
        #pragma unroll
        for (int off = 32; off; off >>= 1) {
            s += __shfl_xor(s, off);
            q += __shfl_xor(q, off);
        }
        const int wave = tid >> 6, lane = tid & 63;
        if (lane == 0) { red[wave] = s; red[4 + wave] = q; }
        __syncthreads();
        s = red[0] + red[1] + red[2] + red[3];
        q = red[4] + red[5] + red[6] + red[7];

        const float mean = s * (1.0f / D_);
        const float var  = q * (1.0f / D_) - mean * mean;
        const float rs   = rsqrtf(var + 1e-5f);

        u16 o[4] __attribute__((aligned(8)));
        #pragma unroll
        for (int i = 0; i < 4; ++i) {
            const int c = tid * 4 + i;
            const float gv = isf ? ((const float*)graw)[c] : bf2f(((const u16*)graw)[c]);
            const float bv = isf ? ((const float*)braw)[c] : bf2f(((const u16*)braw)[c]);
            o[i] = f2bf((xv[i] - mean) * rs * gv + bv);
        }
        *(uint2*)&h[(size_t)row * D_ + tid * 4] = *(uint2*)o;
    } else if (bid < M_ + 1024) {
        // ---- weight transpose+convert ----
        const int w = bid - M_;
        const int z = w >> 8;            // weight index 0..3
        const int t = w & 255;
        const void* Wraw = (z == 0) ? W0 : (z == 1) ? W1 : (z == 2) ? W2 : W3;
        u16* Wt          = (z == 0) ? Wt0 : (z == 1) ? Wt1 : (z == 2) ? Wt2 : Wt3;
        u16 (*tile)[PSTR] = (u16(*)[PSTR])sh;
        const int isf = detect_f32((const u16*)Wraw);
        const int n0 = (t & 15) * 64;
        const int k0 = (t >> 4) * 64;
        const int tr  = tid >> 2;          // 0..63
        const int tc  = (tid & 3) * 16;    // 0,16,32,48

        if (isf) {
            const float* W = (const float*)Wraw;
            #pragma unroll
            for (int i = 0; i < 16; ++i)
                tile[tc + i][tr] = f2bf(W[(size_t)(k0 + tr) * D_ + n0 + tc + i]);
        } else {
            const u16* W = (const u16*)Wraw;
            #pragma unroll
            for (int i = 0; i < 16; ++i)
                tile[tc + i][tr] = W[(size_t)(k0 + tr) * D_ + n0 + tc + i];
        }
        __syncthreads();
        *(uint4*)&Wt[(size_t)(n0 + tr) * D_ + k0 + tc]     = *(uint4*)&tile[tr][tc];
        *(uint4*)&Wt[(size_t)(n0 + tr) * D_ + k0 + tc + 8] = *(uint4*)&tile[tr][tc + 8];
    } else {
        // ---- RoPE table: tab[t*32+i] = {cos, sin}(t * 10000^(-i/32)) ----
        const int gid = (bid - (M_ + 1024)) * 256 + tid;  // 0..65535
        if (gid == 0 && ctr) ctr[0] = 0;                  // reset attn work queue
        const int t = gid >> 5, i = gid & 31;
        const float inv = exp2f(-(float)i * 0.41524101186092f);
        const float ang = (float)t * inv;
        float sv, cv;
        sincosf(ang, &sv, &cv);
        tab[gid] = make_float2(cv, sv);
    }
}

// single-weight transpose (fallback path)
__global__ __launch_bounds__(256) void wconv_kernel(const void* __restrict__ Wraw,
                                                    u16* __restrict__ Wt) {
    __shared__ u16 tile[64][PSTR];
    const int isf = detect_f32((const u16*)Wraw);
    const int n0 = blockIdx.x * 64;
    const int k0 = blockIdx.y * 64;
    const int tid = threadIdx.x;
    const int tr  = tid >> 2;
    const int tc  = (tid & 3) * 16;

    if (isf) {
        const float* W = (const float*)Wraw;
        #pragma unroll
        for (int i = 0; i < 16; ++i)
            tile[tc + i][tr] = f2bf(W[(size_t)(k0 + tr) * D_ + n0 + tc + i]);
    } else {
        const u16* W = (const u16*)Wraw;
        #pragma unroll
        for (int i = 0; i < 16; ++i)
            tile[tc + i][tr] = W[(size_t)(k0 + tr) * D_ + n0 + tc + i];
    }
    __syncthreads();
    *(uint4*)&Wt[(size_t)(n0 + tr) * D_ + k0 + tc]     = *(uint4*)&tile[tr][tc];
    *(uint4*)&Wt[(size_t)(n0 + tr) * D_ + k0 + tc + 8] = *(uint4*)&tile[tr][tc + 8];
}

// --------------------------------------------------- V transpose (per head)
// vtmp (M, D) row-major -> vt (N, H, DH, T)
__global__ __launch_bounds__(256) void vtrans_kernel(const u16* __restrict__ vtmp,
                                                     u16* __restrict__ vt) {
    __shared__ u16 tile[64][PSTR];
    const int bh = blockIdx.y;
    const int b  = bh >> 4;
    const int hh = bh & 15;
    const int t0 = blockIdx.x * 64;
    const int tid = threadIdx.x;
    const int tr  = tid >> 2;          // 0..63
    const int tc  = (tid & 3) * 16;

    #pragma unroll
    for (int i = 0; i < 16; ++i)   // tile[d][t]
        tile[tc + i][tr] = vtmp[(size_t)(b * T_ + t0 + tr) * D_ + hh * DH + tc + i];
    __syncthreads();
    u16* dst = vt + (size_t)bh * DH * T_ + (size_t)tr * T_ + t0;
    *(uint4*)&dst[tc]     = *(uint4*)&tile[tr][tc];
    *(uint4*)&dst[tc + 8] = *(uint4*)&tile[tr][tc + 8];
}

// Staging for BK=32 3-buffer GEMMs: per wave, 2 issues for A + 2 for B.
// LDS layout: rows of 64B (32 bf16), slot = chunk ^ ((row>>1)&3) (16B units)
// -> 2 lanes/granule per 16-lane group on ds_read_b128 (conflict-free).
// Source pre-swizzled: lane l reads global col-chunk (l&3)^((l>>3)&3).
#define STAGE3(As_, Bs_, buf, aPg, bPg, k0, lofs)                                   \
    do {                                                                            \
        gl_lds16((aPg) + (k0),                 &(As_)[buf][(lofs)]);                \
        gl_lds16((aPg) + 16 * D_ + (k0),       &(As_)[buf][(lofs) + 16 * 32]);      \
        gl_lds16((bPg) + (k0),                 &(Bs_)[buf][(lofs)]);                \
        gl_lds16((bPg) + 16 * D_ + (k0),       &(Bs_)[buf][(lofs) + 16 * 32]);      \
    } while (0)

// ---------------------------------------------------------------- fused QKV GEMM
// 128x128 tile, BK=32, 3-BUFFER rotation + COUNTED vmcnt (T4): stage tile
// k+2 while computing k; before the raw s_barrier wait only vmcnt(4) --
// this step's 4 loads stay in flight ACROSS the barrier. LDS 48KB ->
// 3 blocks/CU. Grid 1536 = 6/CU (2 balanced rounds of 3), XCD-chunked.
// Outputs ROW-MAJOR (M, D); Q,K: table RoPE.
__global__ __launch_bounds__(256) void qkv_kernel(const u16* __restrict__ A,
                                                  const u16* __restrict__ Wt3,
                                                  const void* __restrict__ Braw,
                                                  const void* __restrict__ bqr,
                                                  const void* __restrict__ bkr,
                                                  const void* __restrict__ bvr,
                                                  u16* __restrict__ qo,
                                                  u16* __restrict__ ko,
                                                  u16* __restrict__ vo,
                                                  const float2* __restrict__ tab) {
    __shared__ __align__(16) u16 As[3][128 * 32];
    __shared__ __align__(16) u16 Bs[3][128 * 32];

    const int tid   = threadIdx.x;
    const int wave  = tid >> 6;
    const int lane  = tid & 63;
    const int quad  = lane >> 4;
    const int lr    = lane & 15;

    // chunked XCD swizzle: 1536 = 8 * 192
    const int bid = blockIdx.x;
    const int wg  = (bid & 7) * 192 + (bid >> 3);
    const int ntile = (wg % 24) * 128;       // 0..2944
    const int mtile = (wg / 24) * 128;
    const int seg   = ntile >> 10;           // 0=Q 1=K 2=V

    const int isf = detect_f32((const u16*)Braw);

    // staging: issue j covers rows wave*32 + j*16 + (lane>>2); slot lane&3
    const int sr  = lane >> 2;                               // 0..15
    const int scw = 8 * ((lane & 3) ^ ((lane >> 3) & 3));    // pre-swizzled col
    const u16* aPg = A   + (size_t)(mtile + wave * 32 + sr) * D_ + scw;
    const u16* bPg = Wt3 + (size_t)(ntile + wave * 32 + sr) * D_ + scw;
    const int lofs = (wave * 32) * 32;       // wave-uniform LDS offset (u16)

    const int mbase = (wave >> 1) * 64;
    const int nbase = (wave & 1) * 64;
    const int ksl   = (quad ^ ((lr >> 1) & 3)) * 8;   // swizzled read slot (u16)

    f32x4 acc[4][4];
    #pragma unroll
    for (int m = 0; m < 4; ++m)
        #pragma unroll
        for (int n = 0; n < 4; ++n)
            acc[m][n] = (f32x4){0.f, 0.f, 0.f, 0.f};

    // prologue: stage K-tiles 0,1 into bufs 0,1; wait only tile 0 (vmcnt(4))
    STAGE3(As, Bs, 0, aPg, bPg, 0, lofs);
    STAGE3(As, Bs, 1, aPg, bPg, 32, lofs);
    asm volatile("s_waitcnt vmcnt(4)" ::: "memory");
    __builtin_amdgcn_s_barrier();

    int b0 = 0, b1 = 1, b2 = 2;
    for (int kk = 0; kk < 32; ++kk) {
        if (kk + 2 < 32) STAGE3(As, Bs, b2, aPg, bPg, (kk + 2) * 32, lofs);

        bf16x8 af[4], bfr[4];
        #pragma unroll
        for (int m = 0; m < 4; ++m)
            af[m] = *(const bf16x8*)&As[b0][(mbase + m * 16 + lr) * 32 + ksl];
        #pragma unroll
        for (int n = 0; n < 4; ++n)
            bfr[n] = *(const bf16x8*)&Bs[b0][(nbase + n * 16 + lr) * 32 + ksl];

        __builtin_amdgcn_s_setprio(1);
        #pragma unroll
        for (int m = 0; m < 4; ++m)
            #pragma unroll
            for (int n = 0; n < 4; ++n)
                acc[m][n] = __builtin_amdgcn_mfma_f32_16x16x32_bf16(af[m], bfr[n], acc[m][n], 0, 0, 0);
        __builtin_amdgcn_s_setprio(0);

        // counted wait: next buffer (b1) landed; this step's loads stay in flight
        if (kk < 30) asm volatile("s_waitcnt vmcnt(4)" ::: "memory");
        else         asm volatile("s_waitcnt vmcnt(0)" ::: "memory");
        __builtin_amdgcn_s_barrier();

        const int t = b0; b0 = b1; b1 = b2; b2 = t;
    }

    const void* biasraw = (seg == 0) ? bqr : (seg == 1) ? bkr : bvr;
    u16* out            = (seg == 0) ? qo  : (seg == 1) ? ko  : vo;
    const int nloc = (ntile & 1023) + nbase;

    #pragma unroll
    for (int m = 0; m < 4; ++m) {
        #pragma unroll
        for (int n = 0; n < 4; ++n) {
            const int ncl = nloc + n * 16 + lr;       // 0..1023 within segment
            const float bv = isf ? ((const float*)biasraw)[ncl]
                                 : bf2f(((const u16*)biasraw)[ncl]);
            #pragma unroll
            for (int r = 0; r < 4; ++r) {
                const int mrow = mtile + mbase + m * 16 + quad * 4 + r;
                float v = acc[m][n][r] + bv;
                if (seg < 2) {
                    const float other = __shfl_xor(v, 1);
                    const int d = ncl & (DH - 1);
                    const int t = mrow & (T_ - 1);
                    const float2 cs = tab[t * 32 + (d >> 1)];
                    v = (d & 1) ? (other * cs.y + v * cs.x) : (v * cs.x - other * cs.y);
                }
                out[(size_t)mrow * D_ + ncl] = f2bf(v);
            }
        }
    }
}

// ---------------------------------------------------------------- GEMM (3-buffer counted-vmcnt)
// Same structure as qkv_kernel. nwg = nx * 64, divisible by 8.
// mode 0: row-major store; mode 1: V-transposed scatter; mode 2: RoPE scatter
__global__ __launch_bounds__(256) void gemm128_kernel(const u16* __restrict__ A,
                                                      const u16* __restrict__ Bt,
                                                      const void* __restrict__ Braw,
                                                      const void* __restrict__ biasraw,
                                                      void* __restrict__ out,
                                                      const int nx,
                                                      const int mode) {
    __shared__ __align__(16) u16 As[3][128 * 32];
    __shared__ __align__(16) u16 Bs[3][128 * 32];

    const int tid   = threadIdx.x;
    const int wave  = tid >> 6;
    const int lane  = tid & 63;
    const int quad  = lane >> 4;
    const int lr    = lane & 15;

    const int bid = blockIdx.x;
    const int cpx = (nx * (M_ / 128)) >> 3;
    const int wg  = (bid & 7) * cpx + (bid >> 3);
    const int ntile = (wg % nx) * 128;
    const int mtile = (wg / nx) * 128;

    const int isf = detect_f32((const u16*)Braw);

    const int sr  = lane >> 2;
    const int scw = 8 * ((lane & 3) ^ ((lane >> 3) & 3));
    const u16* aPg = A  + (size_t)(mtile + wave * 32 + sr) * D_ + scw;
    const u16* bPg = Bt + (size_t)(ntile + wave * 32 + sr) * D_ + scw;
    const int lofs = (wave * 32) * 32;

    const int mbase = (wave >> 1) * 64;
    const int nbase = (wave & 1) * 64;
    const int ksl   = (quad ^ ((lr >> 1) & 3)) * 8;

    f32x4 acc[4][4];
    #pragma unroll
    for (int m = 0; m < 4; ++m)
        #pragma unroll
        for (int n = 0; n < 4; ++n)
            acc[m][n] = (f32x4){0.f, 0.f, 0.f, 0.f};

    STAGE3(As, Bs, 0, aPg, bPg, 0, lofs);
    STAGE3(As, Bs, 1, aPg, bPg, 32, lofs);
    asm volatile("s_waitcnt vmcnt(4)" ::: "memory");
    __builtin_amdgcn_s_barrier();

    int b0 = 0, b1 = 1, b2 = 2;
    for (int kk = 0; kk < 32; ++kk) {
        if (kk + 2 < 32) STAGE3(As, Bs, b2, aPg, bPg, (kk + 2) * 32, lofs);

        bf16x8 af[4], bfr[4];
        #pragma unroll
        for (int m = 0; m < 4; ++m)
            af[m] = *(const bf16x8*)&As[b0][(mbase + m * 16 + lr) * 32 + ksl];
        #pragma unroll
        for (int n = 0; n < 4; ++n)
            bfr[n] = *(const bf16x8*)&Bs[b0][(nbase + n * 16 + lr) * 32 + ksl];

        __builtin_amdgcn_s_setprio(1);
        #pragma unroll
        for (int m = 0; m < 4; ++m)
            #pragma unroll
            for (int n = 0; n < 4; ++n)
                acc[m][n] = __builtin_amdgcn_mfma_f32_16x16x32_bf16(af[m], bfr[n], acc[m][n], 0, 0, 0);
        __builtin_amdgcn_s_setprio(0);

        if (kk < 30) asm volatile("s_waitcnt vmcnt(4)" ::: "memory");
        else         asm volatile("s_waitcnt vmcnt(0)" ::: "memory");
        __builtin_amdgcn_s_barrier();

        const int t = b0; b0 = b1; b1 = b2; b2 = t;
    }

    #pragma unroll
    for (int m = 0; m < 4; ++m) {
        #pragma unroll
        for (int n = 0; n < 4; ++n) {
            const int ncol = ntile + nbase + n * 16 + lr;
            const float bv = isf ? ((const float*)biasraw)[ncol]
                                 : bf2f(((const u16*)biasraw)[ncol]);
            #pragma unroll
            for (int r = 0; r < 4; ++r) {
                const int mrow = mtile + mbase + m * 16 + quad * 4 + r;
                float v = acc[m][n][r] + bv;
                if (mode == 2) {
                    const float other = __shfl_xor(v, 1);
                    const int d = ncol & (DH - 1);
                    const int t = mrow & (T_ - 1);
                    const int i = d >> 1;
                    const float inv = exp2f(-(float)i * 0.41524101186092f);
                    const float ang = (float)t * inv;
                    float sv, cv;
                    __sincosf(ang, &sv, &cv);
                    v = (d & 1) ? (other * sv + v * cv) : (v * cv - other * sv);
                }
                const int d  = ncol & (DH - 1);
                const int hh = ncol >> 6;
                const int t  = mrow & (T_ - 1);
                const int bb = mrow >> 11;
                if (mode == 0) {
                    if (isf) ((float*)out)[(size_t)mrow * D_ + ncol] = v;
                    else     ((u16*)out)[(size_t)mrow * D_ + ncol] = f2bf(v);
                } else if (mode == 1) {
                    ((u16*)out)[(((size_t)(bb * H_ + hh) * DH) + d) * T_ + t] = f2bf(v);
                } else {
                    ((u16*)out)[(((size_t)(bb * H_ + hh) * T_) + t) * DH + d] = f2bf(v);
                }
            }
        }
    }
}

// ---------------------------------------------------------------- GEMM (no-wt fallback)
__global__ __launch_bounds__(256) void gemm_kernel(const u16* __restrict__ A,
                                                   const void* __restrict__ Braw,
                                                   const void* __restrict__ biasraw,
                                                   void* __restrict__ out,
                                                   const int mode) {
    __shared__ __align__(16) u16 As[128 * 32];
    __shared__ __align__(16) u16 Bs[64 * 32];

    const int tid   = threadIdx.x;
    const int ntile = blockIdx.x * 64;
    const int mtile = blockIdx.y * 128;
    const int wave  = tid >> 6;
    const int lane  = tid & 63;
    const int quad  = lane >> 4;
    const int lr    = lane & 15;

    const int isf = detect_f32((const u16*)Braw);
    const float* Bf = (const float*)Braw;
    const u16*   Bu = (const u16*)Braw;

    f32x4 acc[2][4];
    #pragma unroll
    for (int s = 0; s < 2; ++s)
        #pragma unroll
        for (int n = 0; n < 4; ++n)
            acc[s][n] = (f32x4){0.f, 0.f, 0.f, 0.f};

    const int ar  = tid >> 1;
    const int akb = (tid & 1) * 16;
    const int bn  = tid & 63;
    const int bkb = (tid >> 6) * 8;
    const u16* Arow = A + (size_t)(mtile + ar) * D_ + akb;
    const size_t bcol0 = (size_t)bkb * D_ + ntile + bn;

    for (int k0 = 0; k0 < D_; k0 += 32) {
        *(uint4*)&As[ar * 32 + akb]     = *(const uint4*)(Arow + k0);
        *(uint4*)&As[ar * 32 + akb + 8] = *(const uint4*)(Arow + k0 + 8);
        {
            u16 tmp[8] __attribute__((aligned(16)));
            if (isf) {
                #pragma unroll
                for (int j = 0; j < 8; ++j) tmp[j] = f2bf(Bf[bcol0 + (size_t)(k0 + j) * D_]);
            } else {
                #pragma unroll
                for (int j = 0; j < 8; ++j) tmp[j] = Bu[bcol0 + (size_t)(k0 + j) * D_];
            }
            *(uint4*)&Bs[bn * 32 + bkb] = *(uint4*)tmp;
        }
        __syncthreads();

        const int mbase = wave * 32;
        bf16x8 af0 = *(const bf16x8*)&As[(mbase +      lr) * 32 + quad * 8];
        bf16x8 af1 = *(const bf16x8*)&As[(mbase + 16 + lr) * 32 + quad * 8];
        #pragma unroll
        for (int nt = 0; nt < 4; ++nt) {
            bf16x8 bf = *(const bf16x8*)&Bs[(nt * 16 + lr) * 32 + quad * 8];
            acc[0][nt] = __builtin_amdgcn_mfma_f32_16x16x32_bf16(af0, bf, acc[0][nt], 0, 0, 0);
            acc[1][nt] = __builtin_amdgcn_mfma_f32_16x16x32_bf16(af1, bf, acc[1][nt], 0, 0, 0);
        }
        __syncthreads();
    }

    #pragma unroll
    for (int s2 = 0; s2 < 2; ++s2) {
        #pragma unroll
        for (int nt = 0; nt < 4; ++nt) {
            const int ncol = ntile + nt * 16 + lr;
            const float bv = isf ? ((const float*)biasraw)[ncol]
                                 : bf2f(((const u16*)biasraw)[ncol]);
            #pragma unroll
            for (int r = 0; r < 4; ++r) {
                const int mrow = mtile + wave * 32 + s2 * 16 + quad * 4 + r;
                float v = acc[s2][nt][r] + bv;
                if (mode == 2) {
                    const float other = __shfl_xor(v, 1);
                    const int d = ncol & (DH - 1);
                    const int t = mrow & (T_ - 1);
                    const int i = d >> 1;
                    const float inv = exp2f(-(float)i * 0.41524101186092f);
                    const float ang = (float)t * inv;
                    const float cv = cosf(ang), sv = sinf(ang);
                    v = (d & 1) ? (other * sv + v * cv) : (v * cv - other * sv);
                }
                const int d  = ncol & (DH - 1);
                const int hh = ncol >> 6;
                const int t  = mrow & (T_ - 1);
                const int bb = mrow >> 11;
                if (mode == 0) {
                    if (isf) ((float*)out)[(size_t)mrow * D_ + ncol] = v;
                    else     ((u16*)out)[(size_t)mrow * D_ + ncol] = f2bf(v);
                } else if (mode == 1) {
                    ((u16*)out)[(((size_t)(bb * H_ + hh) * DH) + d) * T_ + t] = f2bf(v);
                } else {
                    ((u16*)out)[(((size_t)(bb * H_ + hh) * T_) + t) * DH + d] = f2bf(v);
                }
            }
        }
    }
}

// ---------------------------------------------------------------- attention
// Persistent-block work-queue flash attention, FIXED-MAX softmax:
//   p = exp2(C2 * rcp(z+1)), z = exp2(s*C1)   -- raw v_exp/v_rcp only
// Work items = 2048 (bh, q-tile) units ordered q-tile DESCENDING (LPT).
// ctr != nullptr: 1024 persistent blocks pull items via device atomicAdd
// (counter zeroed by prep each replay). ctr == nullptr: item = blockIdx.x.
// Inner loop: reg prefetch, 2 barriers/tile, no-barrier wave-private
// softmax->PV, setprio around MFMA.
// rowmajor=1: Q/K are (M, D); rowmajor=0: (N,H,T,DH).
__global__ __launch_bounds__(256) void attn_kernel(const u16* __restrict__ Q,
                                                   const u16* __restrict__ K,
                                                   const u16* __restrict__ Vt,
                                                   const void* __restrict__ lensraw,
                                                   u16* __restrict__ ctx,
                                                   u32* __restrict__ ctr,
                                                   const int rowmajor) {
    __shared__ __align__(16) u16 Ps[64 * PSTR];    // Q staging, then P tile
    __shared__ __align__(16) u16 Ks[64 * PSTR];
    __shared__ __align__(16) u16 Vts[64 * PSTR];   // [dim][key]
    __shared__ int item_s;

    const int tid  = threadIdx.x;
    const int wave = tid >> 6;
    const int lane = tid & 63;
    const int quad = lane >> 4;
    const int lr   = lane & 15;
    const int srow = tid >> 2;          // wave w covers rows 16w..16w+15
    const int scb  = (tid & 3) * 16;
    const int prow = wave * 16 + quad * 4;

    const float C1 = 1.44269504f / 120.0f;   // log2e / 120
    const float C2 = -60.0f * 1.44269504f;   // -60 * log2e

    for (int iter = 0; ; ++iter) {
        if (tid == 0)
            item_s = ctr ? (int)atomicAdd(ctr, 1u)
                         : (iter == 0 ? (int)blockIdx.x : NB * H_ * 32);
        __syncthreads();   // broadcast; also guards LDS reuse across items
        const int item = item_s;
        if (item >= NB * H_ * 32) break;

        // LPT mapping: longest q-tiles first
        const int qt = 31 - (item >> 6);   // 31..0
        const int bh = item & 63;
        const int qs = qt * 64;
        const int b  = bh >> 4;
        const int hh = bh & 15;
        const int len = read_len(lensraw, b);

        const size_t qkstride = rowmajor ? (size_t)D_ : (size_t)DH;
        const size_t qkoff    = rowmajor ? ((size_t)b * T_ * D_ + hh * DH)
                                         : ((size_t)bh * T_ * DH);
        const u16* Qp = Q + qkoff;
        const u16* Kp = K + qkoff;
        const u16* Vb = Vt + (size_t)bh * DH * T_;

        // Q staging (wave-private rows; no barrier needed) + K/V tile 0
        *(uint4*)&Ps[srow * PSTR + scb]     = *(const uint4*)&Qp[(size_t)(qs + srow) * qkstride + scb];
        *(uint4*)&Ps[srow * PSTR + scb + 8] = *(const uint4*)&Qp[(size_t)(qs + srow) * qkstride + scb + 8];
        const bf16x8 qa0 = *(const bf16x8*)&Ps[(wave * 16 + lr) * PSTR + quad * 8];
        const bf16x8 qa1 = *(const bf16x8*)&Ps[(wave * 16 + lr) * PSTR + 32 + quad * 8];
        {
            uint4 k0 = *(const uint4*)&Kp[(size_t)srow * qkstride + scb];
            uint4 k1 = *(const uint4*)&Kp[(size_t)srow * qkstride + scb + 8];
            uint4 v0 = *(const uint4*)&Vb[(size_t)srow * T_ + scb];
            uint4 v1 = *(const uint4*)&Vb[(size_t)srow * T_ + scb + 8];
            *(uint4*)&Ks[srow * PSTR + scb]      = k0;
            *(uint4*)&Ks[srow * PSTR + scb + 8]  = k1;
            *(uint4*)&Vts[srow * PSTR + scb]     = v0;
            *(uint4*)&Vts[srow * PSTR + scb + 8] = v1;
        }
        __syncthreads();

        f32x4 acc[4];
        float l_loc[4] = {0.f, 0.f, 0.f, 0.f};
        #pragma unroll
        for (int nt = 0; nt < 4; ++nt) acc[nt] = (f32x4){0.f, 0.f, 0.f, 0.f};

        const int ktn = min(qs + 63, len - 1) / 64 + 1;

        uint4 kr0, kr1, vr0, vr1;
        for (int kt = 0; kt < ktn; ++kt) {
            const int ks = kt * 64;
            const bool havenext = (kt + 1 < ktn);   // block-uniform

            if (havenext) {
                const int ns = ks + 64;
                kr0 = *(const uint4*)&Kp[(size_t)(ns + srow) * qkstride + scb];
                kr1 = *(const uint4*)&Kp[(size_t)(ns + srow) * qkstride + scb + 8];
                vr0 = *(const uint4*)&Vb[(size_t)srow * T_ + ns + scb];
                vr1 = *(const uint4*)&Vb[(size_t)srow * T_ + ns + scb + 8];
            }

            // QK^T
            f32x4 s[4];
            #pragma unroll
            for (int nt = 0; nt < 4; ++nt) s[nt] = (f32x4){0.f, 0.f, 0.f, 0.f};
            __builtin_amdgcn_s_setprio(1);
            #pragma unroll
            for (int nt = 0; nt < 4; ++nt) {
                bf16x8 kb0 = *(const bf16x8*)&Ks[(nt * 16 + lr) * PSTR + quad * 8];
                bf16x8 kb1 = *(const bf16x8*)&Ks[(nt * 16 + lr) * PSTR + 32 + quad * 8];
                s[nt] = __builtin_amdgcn_mfma_f32_16x16x32_bf16(qa0, kb0, s[nt], 0, 0, 0);
                s[nt] = __builtin_amdgcn_mfma_f32_16x16x32_bf16(qa1, kb1, s[nt], 0, 0, 0);
            }
            __builtin_amdgcn_s_setprio(0);

            // fixed-max softmax; masking only on diagonal / len-boundary tiles
            const bool need_mask = (ks == qs) || (ks + 63 >= len);
            if (!need_mask) {
                #pragma unroll
                for (int r = 0; r < 4; ++r) {
                    #pragma unroll
                    for (int nt = 0; nt < 4; ++nt) {
                        const float z = __builtin_amdgcn_exp2f(s[nt][r] * C1);
                        const float p = __builtin_amdgcn_exp2f(C2 * __builtin_amdgcn_rcpf(z + 1.0f));
                        l_loc[r] += p;
                        Ps[(prow + r) * PSTR + nt * 16 + lr] = f2bf(p);
                    }
                }
            } else {
                #pragma unroll
                for (int r = 0; r < 4; ++r) {
                    const int trow = qs + prow + r;
                    #pragma unroll
                    for (int nt = 0; nt < 4; ++nt) {
                        const float z = __builtin_amdgcn_exp2f(s[nt][r] * C1);
                        float p = __builtin_amdgcn_exp2f(C2 * __builtin_amdgcn_rcpf(z + 1.0f));
                        const int col = ks + nt * 16 + lr;
                        p = (col > trow || col >= len) ? 0.f : p;
                        l_loc[r] += p;
                        Ps[(prow + r) * PSTR + nt * 16 + lr] = f2bf(p);
                    }
                }
            }
            // no barrier: Ps rows are wave-private

            // PV
            bf16x8 pa0 = *(const bf16x8*)&Ps[(wave * 16 + lr) * PSTR + quad * 8];
            bf16x8 pa1 = *(const bf16x8*)&Ps[(wave * 16 + lr) * PSTR + 32 + quad * 8];
            __builtin_amdgcn_s_setprio(1);
            #pragma unroll
            for (int nt = 0; nt < 4; ++nt) {
                bf16x8 vb0 = *(const bf16x8*)&Vts[(nt * 16 + lr) * PSTR + quad * 8];
                bf16x8 vb1 = *(const bf16x8*)&Vts[(nt * 16 + lr) * PSTR + 32 + quad * 8];
                acc[nt] = __builtin_amdgcn_mfma_f32_16x16x32_bf16(pa0, vb0, acc[nt], 0, 0, 0);
                acc[nt] = __builtin_amdgcn_mfma_f32_16x16x32_bf16(pa1, vb1, acc[nt], 0, 0, 0);
            }
            __builtin_amdgcn_s_setprio(0);

            if (havenext) {
                __syncthreads();   // all reads of Ks/Vts done before overwrite
                *(uint4*)&Ks[srow * PSTR + scb]      = kr0;
                *(uint4*)&Ks[srow * PSTR + scb + 8]  = kr1;
                *(uint4*)&Vts[srow * PSTR + scb]     = vr0;
                *(uint4*)&Vts[srow * PSTR + scb + 8] = vr1;
                __syncthreads();   // new tile visible
            }
        }

        // epilogue: reduce l across the 16 lanes of each row group, write ctx
        #pragma unroll
        for (int r = 0; r < 4; ++r) {
            float l = l_loc[r];
            #pragma unroll
            for (int off = 1; off < 16; off <<= 1) l += __shfl_xor(l, off);
            const float invl = (l > 0.f) ? (1.0f / l) : 0.f;
            const int qrow = prow + r;
            #pragma unroll
            for (int nt = 0; nt < 4; ++nt) {
                ctx[(size_t)(b * T_ + qs + qrow) * D_ + hh * DH + nt * 16 + lr] =
                    f2bf(acc[nt][r] * invl);
            }
        }
    }
}

// ---------------------------------------------------------------- launch
extern "C" void kernel_launch(void* const* d_in, const int* in_sizes, int n_in,
                              void* d_out, int out_size, void* d_ws, size_t ws_size,
                              hipStream_t stream) {
    // ws layout: [h][q][k][vt : 16MB each][wtq|wtk|wtv|wto : 2MB each]
    //            [vtmp 16MB][rope table 512KB][work-queue counter 64B]
    u16* h = (u16*)d_ws;
    const size_t MD = (size_t)M_ * D_;
    const size_t WD = (size_t)D_ * D_;
    u16* q  = h + MD;
    u16* k  = q + MD;
    u16* vt = k + MD;
    const bool havewt  = ws_size >= (4 * MD + 4 * WD) * sizeof(u16);
    const bool havebig = ws_size >= (5 * MD + 4 * WD) * sizeof(u16)
                                    + (size_t)T_ * 32 * sizeof(float2) + 64;
    u16* wtq = havewt ? (vt + MD)  : nullptr;
    u16* wtk = havewt ? (wtq + WD) : nullptr;
    u16* wtv = havewt ? (wtk + WD) : nullptr;
    u16* wto = havewt ? (wtv + WD) : nullptr;
    u16* vtmp = havebig ? (wto + WD) : nullptr;
    float2* tab = havebig ? (float2*)(vtmp + MD) : nullptr;
    u32* ctr = havebig ? (u32*)(tab + (size_t)T_ * 32) : nullptr;

    if (havebig) {
        // fused ln + weight-transpose + rope table (+ queue reset)
        prep_kernel<<<M_ + 1024 + 256, 256, 0, stream>>>(
            d_in[0], d_in[1], d_in[2], h,
            d_in[3], d_in[5], d_in[7], d_in[9], wtq, wtk, wtv, wto, tab, ctr);

        qkv_kernel<<<1536, 256, 0, stream>>>(
            h, wtq, d_in[3], d_in[4], d_in[6], d_in[8], q, k, vtmp, tab);

        vtrans_kernel<<<dim3(T_ / 64, NB * H_), 256, 0, stream>>>(vtmp, vt);

        attn_kernel<<<1024, 256, 0, stream>>>(q, k, vt, d_in[13], h, ctr, 1);

        gemm128_kernel<<<8 * (M_ / 128), 256, 0, stream>>>(
            h, wto, d_in[9], d_in[10], d_out, 8, 0);
    } else if (havewt) {
        // fallback: separate kernels, scatter epilogues, static attn mapping
        prep_kernel<<<M_, 256, 0, stream>>>(
            d_in[0], d_in[1], d_in[2], h,
            d_in[3], d_in[5], d_in[7], d_in[9], wtq, wtk, wtv, wto, nullptr, nullptr);
        dim3 wgrid(D_ / 64, D_ / 64);
        wconv_kernel<<<wgrid, 256, 0, stream>>>(d_in[3], wtq);
        wconv_kernel<<<wgrid, 256, 0, stream>>>(d_in[5], wtk);
        wconv_kernel<<<wgrid, 256, 0, stream>>>(d_in[7], wtv);
        wconv_kernel<<<wgrid, 256, 0, stream>>>(d_in[9], wto);

        const int g1 = 8 * (M_ / 128);
        gemm128_kernel<<<g1, 256, 0, stream>>>(h, wtq, d_in[3], d_in[4], q, 8, 2);
        gemm128_kernel<<<g1, 256, 0, stream>>>(h, wtk, d_in[5], d_in[6], k, 8, 2);
        gemm128_kernel<<<g1, 256, 0, stream>>>(h, wtv, d_in[7], d_in[8], vt, 8, 1);

        attn_kernel<<<NB * H_ * 32, 256, 0, stream>>>(q, k, vt, d_in[13], h, nullptr, 0);

        gemm128_kernel<<<g1, 256, 0, stream>>>(h, wto, d_in[9], d_in[10], d_out, 8, 0);
    } else {
        prep_kernel<<<M_, 256, 0, stream>>>(
            d_in[0], d_in[1], d_in[2], h,
            d_in[3], d_in[5], d_in[7], d_in[9], nullptr, nullptr, nullptr, nullptr, nullptr, nullptr);
        dim3 ggrid(D_ / 64, M_ / 128);
        gemm_kernel<<<ggrid, 256, 0, stream>>>(h, d_in[3], d_in[4], q, 2);
        gemm_kernel<<<ggrid, 256, 0, stream>>>(h, d_in[5], d_in[6], k, 2);
        gemm_kernel<<<ggrid, 256, 0, stream>>>(h, d_in[7], d_in[8], vt, 1);

        attn_kernel<<<NB * H_ * 32, 256, 0, stream>>>(q, k, vt, d_in[13], h, nullptr, 0);

        gemm_kernel<<<ggrid, 256, 0, stream>>>(h, d_in[9], d_in[10], d_out, 0);
    }
}